// Round 1
// baseline (781.142 us; speedup 1.0000x reference)
//
#include <hip/hip_runtime.h>

#define S_ 2048
#define B_ 2
#define E_ 1024
#define H_ 16

typedef __bf16 bf16x8 __attribute__((ext_vector_type(8)));
typedef float f32x4 __attribute__((ext_vector_type(4)));
typedef unsigned short us4_t __attribute__((ext_vector_type(4)));

static __device__ __forceinline__ unsigned short f2bf(float x) {
  union { float f; unsigned u; } v; v.f = x;
  unsigned r = v.u + 0x7fffu + ((v.u >> 16) & 1u);
  return (unsigned short)(r >> 16);
}
static __device__ __forceinline__ float bf2f(unsigned short h) {
  union { unsigned u; float f; } v; v.u = ((unsigned)h) << 16;
  return v.f;
}

// ---------------- elementwise split / convert ----------------
__global__ void k_split2(const float* __restrict__ src, unsigned short* __restrict__ hi,
                         unsigned short* __restrict__ lo, int n) {
  int i = blockIdx.x * blockDim.x + threadIdx.x;
  int st = gridDim.x * blockDim.x;
  for (; i < n; i += st) {
    float x = src[i];
    unsigned short h = f2bf(x);
    hi[i] = h;
    lo[i] = f2bf(x - bf2f(h));
  }
}

__global__ void k_cvt(const float* __restrict__ src, unsigned short* __restrict__ dst, int n) {
  int i = blockIdx.x * blockDim.x + threadIdx.x;
  int st = gridDim.x * blockDim.x;
  for (; i < n; i += st) dst[i] = f2bf(src[i]);
}

// ---------------- q/k projection: 3-term split GEMM ----------------
// C = (Ah+Al) @ (Wh+Wl)^T (+bias) (*scale for q), re-split into hi/lo bf16.
__launch_bounds__(256, 2)
__global__ void k_proj_qk(const unsigned short* __restrict__ qxh, const unsigned short* __restrict__ qxl,
                          const unsigned short* __restrict__ kxh, const unsigned short* __restrict__ kxl,
                          const unsigned short* __restrict__ wh, const unsigned short* __restrict__ wl,
                          const float* __restrict__ bias,
                          unsigned short* __restrict__ qh, unsigned short* __restrict__ ql,
                          unsigned short* __restrict__ kh, unsigned short* __restrict__ kl) {
  const int z = blockIdx.z;
  const unsigned short* Ah = z ? kxh : qxh;
  const unsigned short* Al = z ? kxl : qxl;
  const unsigned short* Bh = wh + (size_t)z * (1024 * 1024);
  const unsigned short* Bl = wl + (size_t)z * (1024 * 1024);
  unsigned short* Ch = z ? kh : qh;
  unsigned short* Cl = z ? kl : ql;
  const float* bia = bias + z * 1024;
  const float scale = z ? 1.0f : 0.125f;

  __shared__ unsigned short sAh[128][40], sAl[128][40], sBh[128][40], sBl[128][40];

  const int t = threadIdx.x;
  const int wid = t >> 6, l = t & 63, g = l >> 4, c = l & 15;
  const int wr = wid >> 1, wc = wid & 1;
  const int mb = blockIdx.x * 128, nb = blockIdx.y * 128;
  const int sr = t >> 1, sc = (t & 1) * 16;

  f32x4 acc[4][4] = {};

  for (int k0 = 0; k0 < 1024; k0 += 32) {
    __syncthreads();
    {
      const unsigned short* pah = Ah + (size_t)(mb + sr) * 1024 + k0 + sc;
      const unsigned short* pal = Al + (size_t)(mb + sr) * 1024 + k0 + sc;
      const unsigned short* pbh = Bh + (size_t)(nb + sr) * 1024 + k0 + sc;
      const unsigned short* pbl = Bl + (size_t)(nb + sr) * 1024 + k0 + sc;
      *(bf16x8*)&sAh[sr][sc]     = *(const bf16x8*)pah;
      *(bf16x8*)&sAh[sr][sc + 8] = *(const bf16x8*)(pah + 8);
      *(bf16x8*)&sAl[sr][sc]     = *(const bf16x8*)pal;
      *(bf16x8*)&sAl[sr][sc + 8] = *(const bf16x8*)(pal + 8);
      *(bf16x8*)&sBh[sr][sc]     = *(const bf16x8*)pbh;
      *(bf16x8*)&sBh[sr][sc + 8] = *(const bf16x8*)(pbh + 8);
      *(bf16x8*)&sBl[sr][sc]     = *(const bf16x8*)pbl;
      *(bf16x8*)&sBl[sr][sc + 8] = *(const bf16x8*)(pbl + 8);
    }
    __syncthreads();
    bf16x8 afh[4], afl[4], bfh[4], bfl[4];
    #pragma unroll
    for (int i = 0; i < 4; ++i) {
      afh[i] = *(const bf16x8*)&sAh[wr * 64 + i * 16 + c][g * 8];
      afl[i] = *(const bf16x8*)&sAl[wr * 64 + i * 16 + c][g * 8];
      bfh[i] = *(const bf16x8*)&sBh[wc * 64 + i * 16 + c][g * 8];
      bfl[i] = *(const bf16x8*)&sBl[wc * 64 + i * 16 + c][g * 8];
    }
    #pragma unroll
    for (int i = 0; i < 4; ++i)
      #pragma unroll
      for (int j = 0; j < 4; ++j) {
        acc[i][j] = __builtin_amdgcn_mfma_f32_16x16x32_bf16(afh[i], bfh[j], acc[i][j], 0, 0, 0);
        acc[i][j] = __builtin_amdgcn_mfma_f32_16x16x32_bf16(afh[i], bfl[j], acc[i][j], 0, 0, 0);
        acc[i][j] = __builtin_amdgcn_mfma_f32_16x16x32_bf16(afl[i], bfh[j], acc[i][j], 0, 0, 0);
      }
  }
  #pragma unroll
  for (int i = 0; i < 4; ++i)
    #pragma unroll
    for (int j = 0; j < 4; ++j)
      #pragma unroll
      for (int rr = 0; rr < 4; ++rr) {
        int m = mb + wr * 64 + i * 16 + 4 * g + rr;
        int n = nb + wc * 64 + j * 16 + c;
        float v = (acc[i][j][rr] + bia[n]) * scale;
        unsigned short hh = f2bf(v);
        size_t idx = (size_t)m * 1024 + n;
        Ch[idx] = hh;
        Cl[idx] = f2bf(v - bf2f(hh));
      }
}

// ---------------- v projection, writes V^T layout: VT[b][e'][j] ----------------
__launch_bounds__(256, 2)
__global__ void k_proj_v(const unsigned short* __restrict__ wv, const unsigned short* __restrict__ vx,
                         const float* __restrict__ bias, unsigned short* __restrict__ VT) {
  __shared__ unsigned short sA[128][40], sB[128][40];
  const int t = threadIdx.x;
  const int wid = t >> 6, l = t & 63, g = l >> 4, c = l & 15;
  const int wr = wid >> 1, wc = wid & 1;
  const int mb = blockIdx.x * 128;   // e' base
  const int nb = blockIdx.y * 128;   // n = b*2048 + j
  const int bb = nb >> 11;
  const int jb = nb & 2047;
  const int sr = t >> 1, sc = (t & 1) * 16;

  f32x4 acc[4][4] = {};
  for (int k0 = 0; k0 < 1024; k0 += 32) {
    __syncthreads();
    {
      const unsigned short* pa = wv + (size_t)(mb + sr) * 1024 + k0 + sc;
      const unsigned short* pbp = vx + ((size_t)(jb + sr) * 2 + bb) * 1024 + k0 + sc;
      *(bf16x8*)&sA[sr][sc]     = *(const bf16x8*)pa;
      *(bf16x8*)&sA[sr][sc + 8] = *(const bf16x8*)(pa + 8);
      *(bf16x8*)&sB[sr][sc]     = *(const bf16x8*)pbp;
      *(bf16x8*)&sB[sr][sc + 8] = *(const bf16x8*)(pbp + 8);
    }
    __syncthreads();
    bf16x8 af[4], bfr[4];
    #pragma unroll
    for (int i = 0; i < 4; ++i) {
      af[i]  = *(const bf16x8*)&sA[wr * 64 + i * 16 + c][g * 8];
      bfr[i] = *(const bf16x8*)&sB[wc * 64 + i * 16 + c][g * 8];
    }
    #pragma unroll
    for (int i = 0; i < 4; ++i)
      #pragma unroll
      for (int j = 0; j < 4; ++j)
        acc[i][j] = __builtin_amdgcn_mfma_f32_16x16x32_bf16(af[i], bfr[j], acc[i][j], 0, 0, 0);
  }
  #pragma unroll
  for (int i = 0; i < 4; ++i)
    #pragma unroll
    for (int j = 0; j < 4; ++j)
      #pragma unroll
      for (int rr = 0; rr < 4; ++rr) {
        int m = mb + wr * 64 + i * 16 + 4 * g + rr;
        int jj = jb + wc * 64 + j * 16 + c;
        float v = acc[i][j][rr] + bias[2048 + m];
        VT[(size_t)bb * (1024 * 2048) + (size_t)m * 2048 + jj] = f2bf(v);
      }
}

// ---------------- attention: scores (split-precision) + bias + softmax ----------------
__launch_bounds__(256, 2)
__global__ void k_attn(const unsigned short* __restrict__ qh, const unsigned short* __restrict__ ql,
                       const unsigned short* __restrict__ kh, const unsigned short* __restrict__ kl,
                       const float* __restrict__ posb, float* __restrict__ attn) {
  const int bid = blockIdx.x;
  const int qt = bid & 127;
  const int h = (bid >> 7) & 15;
  const int b = bid >> 11;
  const int t = threadIdx.x;
  const int wid = t >> 6, l = t & 63, g = l >> 4, c = l & 15;

  const size_t qoff = ((size_t)(qt * 16 + c) * 2 + b) * 1024 + h * 64 + g * 8;
  const bf16x8 qfh0 = *(const bf16x8*)(qh + qoff);
  const bf16x8 qfh1 = *(const bf16x8*)(qh + qoff + 32);
  const bf16x8 qfl0 = *(const bf16x8*)(ql + qoff);
  const bf16x8 qfl1 = *(const bf16x8*)(ql + qoff + 32);

  f32x4 acc[32] = {};
  const int jb0 = wid * 512;
  #pragma unroll
  for (int tt = 0; tt < 32; ++tt) {
    const size_t koff = ((size_t)(jb0 + tt * 16 + c) * 2 + b) * 1024 + h * 64 + g * 8;
    bf16x8 kfh0 = *(const bf16x8*)(kh + koff);
    bf16x8 kfh1 = *(const bf16x8*)(kh + koff + 32);
    bf16x8 kfl0 = *(const bf16x8*)(kl + koff);
    bf16x8 kfl1 = *(const bf16x8*)(kl + koff + 32);
    acc[tt] = __builtin_amdgcn_mfma_f32_16x16x32_bf16(qfh0, kfh0, acc[tt], 0, 0, 0);
    acc[tt] = __builtin_amdgcn_mfma_f32_16x16x32_bf16(qfh1, kfh1, acc[tt], 0, 0, 0);
    acc[tt] = __builtin_amdgcn_mfma_f32_16x16x32_bf16(qfh0, kfl0, acc[tt], 0, 0, 0);
    acc[tt] = __builtin_amdgcn_mfma_f32_16x16x32_bf16(qfh1, kfl1, acc[tt], 0, 0, 0);
    acc[tt] = __builtin_amdgcn_mfma_f32_16x16x32_bf16(qfl0, kfh0, acc[tt], 0, 0, 0);
    acc[tt] = __builtin_amdgcn_mfma_f32_16x16x32_bf16(qfl1, kfh1, acc[tt], 0, 0, 0);
  }

  const float* pbr = posb + (size_t)b * S_ * S_ + (size_t)(qt * 16) * S_;
  float lmax[4] = {-3e38f, -3e38f, -3e38f, -3e38f};
  #pragma unroll
  for (int tt = 0; tt < 32; ++tt) {
    int col = jb0 + tt * 16 + c;
    #pragma unroll
    for (int rr = 0; rr < 4; ++rr) {
      float v = acc[tt][rr] + pbr[(size_t)(4 * g + rr) * S_ + col];
      acc[tt][rr] = v;
      lmax[rr] = fmaxf(lmax[rr], v);
    }
  }
  #pragma unroll
  for (int rr = 0; rr < 4; ++rr) {
    lmax[rr] = fmaxf(lmax[rr], __shfl_xor(lmax[rr], 1, 64));
    lmax[rr] = fmaxf(lmax[rr], __shfl_xor(lmax[rr], 2, 64));
    lmax[rr] = fmaxf(lmax[rr], __shfl_xor(lmax[rr], 4, 64));
    lmax[rr] = fmaxf(lmax[rr], __shfl_xor(lmax[rr], 8, 64));
  }
  __shared__ float red[4][16];
  if (c == 0) {
    #pragma unroll
    for (int rr = 0; rr < 4; ++rr) red[wid][4 * g + rr] = lmax[rr];
  }
  __syncthreads();
  float mrow[4];
  #pragma unroll
  for (int rr = 0; rr < 4; ++rr)
    mrow[rr] = fmaxf(fmaxf(red[0][4 * g + rr], red[1][4 * g + rr]),
                     fmaxf(red[2][4 * g + rr], red[3][4 * g + rr]));
  __syncthreads();
  float lsum[4] = {0.f, 0.f, 0.f, 0.f};
  #pragma unroll
  for (int tt = 0; tt < 32; ++tt) {
    #pragma unroll
    for (int rr = 0; rr < 4; ++rr) {
      float p = __expf(acc[tt][rr] - mrow[rr]);
      acc[tt][rr] = p;
      lsum[rr] += p;
    }
  }
  #pragma unroll
  for (int rr = 0; rr < 4; ++rr) {
    lsum[rr] += __shfl_xor(lsum[rr], 1, 64);
    lsum[rr] += __shfl_xor(lsum[rr], 2, 64);
    lsum[rr] += __shfl_xor(lsum[rr], 4, 64);
    lsum[rr] += __shfl_xor(lsum[rr], 8, 64);
  }
  if (c == 0) {
    #pragma unroll
    for (int rr = 0; rr < 4; ++rr) red[wid][4 * g + rr] = lsum[rr];
  }
  __syncthreads();
  float inv[4];
  #pragma unroll
  for (int rr = 0; rr < 4; ++rr)
    inv[rr] = 1.0f / (red[0][4 * g + rr] + red[1][4 * g + rr] +
                      red[2][4 * g + rr] + red[3][4 * g + rr]);
  float* arow = attn + ((size_t)(b * 16 + h) * S_ + qt * 16) * S_;
  #pragma unroll
  for (int tt = 0; tt < 32; ++tt) {
    int col = jb0 + tt * 16 + c;
    #pragma unroll
    for (int rr = 0; rr < 4; ++rr)
      arow[(size_t)(4 * g + rr) * S_ + col] = acc[tt][rr] * inv[rr];
  }
}

// ---------------- PV: out_core = attn @ V  (reads attn f32, VT bf16) ----------------
__launch_bounds__(256, 2)
__global__ void k_pv(const float* __restrict__ attn, const unsigned short* __restrict__ VT,
                     unsigned short* __restrict__ oc) {
  __shared__ unsigned short sA[128][72];
  __shared__ unsigned short sB[64][72];
  const int t = threadIdx.x;
  const int wid = t >> 6, l = t & 63, g = l >> 4, c = l & 15;
  const int rb = blockIdx.x;
  const int bh = blockIdx.y;
  const int b = bh >> 4, h = bh & 15;
  const int rowb = rb * 128;
  const float* P = attn + (size_t)bh * S_ * S_;
  const unsigned short* Vp = VT + ((size_t)b * 1024 + h * 64) * 2048;

  f32x4 acc[2][4] = {};
  for (int k0 = 0; k0 < 2048; k0 += 64) {
    __syncthreads();
    #pragma unroll
    for (int it = 0; it < 8; ++it) {
      int idx = it * 1024 + t * 4;
      int r = idx >> 6, cc = idx & 63;
      f32x4 v = *(const f32x4*)(P + (size_t)(rowb + r) * S_ + k0 + cc);
      us4_t o;
      o[0] = f2bf(v[0]); o[1] = f2bf(v[1]); o[2] = f2bf(v[2]); o[3] = f2bf(v[3]);
      *(us4_t*)&sA[r][cc] = o;
    }
    #pragma unroll
    for (int it = 0; it < 2; ++it) {
      int idx = it * 2048 + t * 8;
      int r = idx >> 6, cc = idx & 63;
      *(bf16x8*)&sB[r][cc] = *(const bf16x8*)(Vp + (size_t)r * 2048 + k0 + cc);
    }
    __syncthreads();
    bf16x8 af[2][2], bfr[4][2];
    #pragma unroll
    for (int i = 0; i < 2; ++i)
      #pragma unroll
      for (int ck = 0; ck < 2; ++ck)
        af[i][ck] = *(const bf16x8*)&sA[wid * 32 + i * 16 + c][ck * 32 + g * 8];
    #pragma unroll
    for (int j = 0; j < 4; ++j)
      #pragma unroll
      for (int ck = 0; ck < 2; ++ck)
        bfr[j][ck] = *(const bf16x8*)&sB[j * 16 + c][ck * 32 + g * 8];
    #pragma unroll
    for (int i = 0; i < 2; ++i)
      #pragma unroll
      for (int j = 0; j < 4; ++j) {
        acc[i][j] = __builtin_amdgcn_mfma_f32_16x16x32_bf16(af[i][0], bfr[j][0], acc[i][j], 0, 0, 0);
        acc[i][j] = __builtin_amdgcn_mfma_f32_16x16x32_bf16(af[i][1], bfr[j][1], acc[i][j], 0, 0, 0);
      }
  }
  #pragma unroll
  for (int i = 0; i < 2; ++i)
    #pragma unroll
    for (int j = 0; j < 4; ++j)
      #pragma unroll
      for (int rr = 0; rr < 4; ++rr) {
        int row = rowb + wid * 32 + i * 16 + 4 * g + rr;
        int d = j * 16 + c;
        oc[((size_t)row * 2 + b) * 1024 + h * 64 + d] = f2bf(acc[i][j][rr]);
      }
}

// ---------------- out projection ----------------
__launch_bounds__(256, 2)
__global__ void k_outproj(const unsigned short* __restrict__ oc, const unsigned short* __restrict__ ow,
                          const float* __restrict__ ob, float* __restrict__ out) {
  __shared__ unsigned short sA[128][40], sB[128][40];
  const int t = threadIdx.x;
  const int wid = t >> 6, l = t & 63, g = l >> 4, c = l & 15;
  const int wr = wid >> 1, wc = wid & 1;
  const int mb = blockIdx.x * 128, nb = blockIdx.y * 128;
  const int sr = t >> 1, sc = (t & 1) * 16;

  f32x4 acc[4][4] = {};
  for (int k0 = 0; k0 < 1024; k0 += 32) {
    __syncthreads();
    {
      const unsigned short* pa = oc + (size_t)(mb + sr) * 1024 + k0 + sc;
      const unsigned short* pbp = ow + (size_t)(nb + sr) * 1024 + k0 + sc;
      *(bf16x8*)&sA[sr][sc]     = *(const bf16x8*)pa;
      *(bf16x8*)&sA[sr][sc + 8] = *(const bf16x8*)(pa + 8);
      *(bf16x8*)&sB[sr][sc]     = *(const bf16x8*)pbp;
      *(bf16x8*)&sB[sr][sc + 8] = *(const bf16x8*)(pbp + 8);
    }
    __syncthreads();
    bf16x8 af[4], bfr[4];
    #pragma unroll
    for (int i = 0; i < 4; ++i) {
      af[i]  = *(const bf16x8*)&sA[wr * 64 + i * 16 + c][g * 8];
      bfr[i] = *(const bf16x8*)&sB[wc * 64 + i * 16 + c][g * 8];
    }
    #pragma unroll
    for (int i = 0; i < 4; ++i)
      #pragma unroll
      for (int j = 0; j < 4; ++j)
        acc[i][j] = __builtin_amdgcn_mfma_f32_16x16x32_bf16(af[i], bfr[j], acc[i][j], 0, 0, 0);
  }
  #pragma unroll
  for (int i = 0; i < 4; ++i)
    #pragma unroll
    for (int j = 0; j < 4; ++j)
      #pragma unroll
      for (int rr = 0; rr < 4; ++rr) {
        int m = mb + wr * 64 + i * 16 + 4 * g + rr;
        int n = nb + wc * 64 + j * 16 + c;
        out[(size_t)m * 1024 + n] = acc[i][j][rr] + ob[n];
      }
}

extern "C" void kernel_launch(void* const* d_in, const int* in_sizes, int n_in,
                              void* d_out, int out_size, void* d_ws, size_t ws_size,
                              hipStream_t stream) {
  (void)in_sizes; (void)n_in; (void)out_size; (void)ws_size;
  const float* query = (const float*)d_in[0];
  const float* keyi  = (const float*)d_in[1];
  const float* value = (const float*)d_in[2];
  const float* posb  = (const float*)d_in[3];
  const float* ipw   = (const float*)d_in[4];
  const float* ipb   = (const float*)d_in[5];
  const float* outw  = (const float*)d_in[6];
  const float* outb  = (const float*)d_in[7];
  float* out = (float*)d_out;
  float* attn = out + (size_t)S_ * B_ * E_;

  char* ws = (char*)d_ws;
  size_t off = 0;
  auto alloc = [&](size_t bytes) -> void* {
    void* p = ws + off;
    off += (bytes + 255) & ~(size_t)255;
    return p;
  };
  const size_t NTOK = (size_t)S_ * B_;  // 4096
  unsigned short* qxh = (unsigned short*)alloc(NTOK * 1024 * 2);
  unsigned short* qxl = (unsigned short*)alloc(NTOK * 1024 * 2);
  unsigned short* kxh = (unsigned short*)alloc(NTOK * 1024 * 2);
  unsigned short* kxl = (unsigned short*)alloc(NTOK * 1024 * 2);
  unsigned short* vx  = (unsigned short*)alloc(NTOK * 1024 * 2);
  unsigned short* wh  = (unsigned short*)alloc((size_t)2048 * 1024 * 2);
  unsigned short* wl  = (unsigned short*)alloc((size_t)2048 * 1024 * 2);
  unsigned short* wv  = (unsigned short*)alloc((size_t)1024 * 1024 * 2);
  unsigned short* ow  = (unsigned short*)alloc((size_t)1024 * 1024 * 2);
  unsigned short* qh  = (unsigned short*)alloc(NTOK * 1024 * 2);
  unsigned short* ql  = (unsigned short*)alloc(NTOK * 1024 * 2);
  unsigned short* kh  = (unsigned short*)alloc(NTOK * 1024 * 2);
  unsigned short* kl  = (unsigned short*)alloc(NTOK * 1024 * 2);
  unsigned short* VT  = (unsigned short*)alloc((size_t)2 * 1024 * 2048 * 2);
  unsigned short* oc  = (unsigned short*)alloc(NTOK * 1024 * 2);

  const int n1 = (int)(NTOK * 1024);  // 4194304
  k_split2<<<2048, 256, 0, stream>>>(query, qxh, qxl, n1);
  k_split2<<<2048, 256, 0, stream>>>(keyi, kxh, kxl, n1);
  k_cvt<<<2048, 256, 0, stream>>>(value, vx, n1);
  k_split2<<<1024, 256, 0, stream>>>(ipw, wh, wl, 2048 * 1024);
  k_cvt<<<512, 256, 0, stream>>>(ipw + 2048 * 1024, wv, 1024 * 1024);
  k_cvt<<<512, 256, 0, stream>>>(outw, ow, 1024 * 1024);

  k_proj_qk<<<dim3(32, 8, 2), 256, 0, stream>>>(qxh, qxl, kxh, kxl, wh, wl, ipb, qh, ql, kh, kl);
  k_proj_v<<<dim3(8, 32), 256, 0, stream>>>(wv, vx, ipb, VT);
  k_attn<<<4096, 256, 0, stream>>>(qh, ql, kh, kl, posb, attn);
  k_pv<<<dim3(16, 32), 256, 0, stream>>>(attn, VT, oc);
  k_outproj<<<dim3(32, 8), 256, 0, stream>>>(oc, ow, outb, out);
}

// Round 2
// 674.099 us; speedup vs baseline: 1.1588x; 1.1588x over previous
//
#include <hip/hip_runtime.h>

#define S_ 2048
#define B_ 2
#define E_ 1024
#define H_ 16

typedef __bf16 bf16x8 __attribute__((ext_vector_type(8)));
typedef float f32x4 __attribute__((ext_vector_type(4)));
typedef unsigned short us4_t __attribute__((ext_vector_type(4)));

static __device__ __forceinline__ unsigned short f2bf(float x) {
  union { float f; unsigned u; } v; v.f = x;
  unsigned r = v.u + 0x7fffu + ((v.u >> 16) & 1u);
  return (unsigned short)(r >> 16);
}
static __device__ __forceinline__ float bf2f(unsigned short h) {
  union { unsigned u; float f; } v; v.u = ((unsigned)h) << 16;
  return v.f;
}
static __device__ __forceinline__ unsigned pk_bf16(float a, float b) {
  // dst.lo = bf16(a), dst.hi = bf16(b)
  unsigned r;
  asm("v_cvt_pk_bf16_f32 %0, %1, %2" : "=v"(r) : "v"(a), "v"(b));
  return r;
}

// ---------------- elementwise split / convert (vectorized) ----------------
__global__ void k_split2(const float* __restrict__ src, unsigned short* __restrict__ hi,
                         unsigned short* __restrict__ lo, int n4) {
  int i = blockIdx.x * blockDim.x + threadIdx.x;
  int st = gridDim.x * blockDim.x;
  for (; i < n4; i += st) {
    f32x4 x = ((const f32x4*)src)[i];
    us4_t h, lw;
    #pragma unroll
    for (int j = 0; j < 4; ++j) {
      unsigned short hh = f2bf(x[j]);
      h[j] = hh;
      lw[j] = f2bf(x[j] - bf2f(hh));
    }
    ((us4_t*)hi)[i] = h;
    ((us4_t*)lo)[i] = lw;
  }
}

__global__ void k_cvt(const float* __restrict__ src, unsigned short* __restrict__ dst, int n4) {
  int i = blockIdx.x * blockDim.x + threadIdx.x;
  int st = gridDim.x * blockDim.x;
  for (; i < n4; i += st) {
    f32x4 x = ((const f32x4*)src)[i];
    us4_t h;
    #pragma unroll
    for (int j = 0; j < 4; ++j) h[j] = f2bf(x[j]);
    ((us4_t*)dst)[i] = h;
  }
}

// ---------------- q/k projection: 3-term split GEMM ----------------
__launch_bounds__(256, 2)
__global__ void k_proj_qk(const unsigned short* __restrict__ qxh, const unsigned short* __restrict__ qxl,
                          const unsigned short* __restrict__ kxh, const unsigned short* __restrict__ kxl,
                          const unsigned short* __restrict__ wh, const unsigned short* __restrict__ wl,
                          const float* __restrict__ bias,
                          unsigned short* __restrict__ qh, unsigned short* __restrict__ ql,
                          unsigned short* __restrict__ kh, unsigned short* __restrict__ kl) {
  const int z = blockIdx.z;
  const unsigned short* Ah = z ? kxh : qxh;
  const unsigned short* Al = z ? kxl : qxl;
  const unsigned short* Bh = wh + (size_t)z * (1024 * 1024);
  const unsigned short* Bl = wl + (size_t)z * (1024 * 1024);
  unsigned short* Ch = z ? kh : qh;
  unsigned short* Cl = z ? kl : ql;
  const float* bia = bias + z * 1024;
  const float scale = z ? 1.0f : 0.125f;

  __shared__ unsigned short sAh[128][40], sAl[128][40], sBh[128][40], sBl[128][40];

  const int t = threadIdx.x;
  const int wid = t >> 6, l = t & 63, g = l >> 4, c = l & 15;
  const int wr = wid >> 1, wc = wid & 1;
  const int mb = blockIdx.x * 128, nb = blockIdx.y * 128;
  const int sr = t >> 1, sc = (t & 1) * 16;

  f32x4 acc[4][4] = {};

  for (int k0 = 0; k0 < 1024; k0 += 32) {
    __syncthreads();
    {
      const unsigned short* pah = Ah + (size_t)(mb + sr) * 1024 + k0 + sc;
      const unsigned short* pal = Al + (size_t)(mb + sr) * 1024 + k0 + sc;
      const unsigned short* pbh = Bh + (size_t)(nb + sr) * 1024 + k0 + sc;
      const unsigned short* pbl = Bl + (size_t)(nb + sr) * 1024 + k0 + sc;
      *(bf16x8*)&sAh[sr][sc]     = *(const bf16x8*)pah;
      *(bf16x8*)&sAh[sr][sc + 8] = *(const bf16x8*)(pah + 8);
      *(bf16x8*)&sAl[sr][sc]     = *(const bf16x8*)pal;
      *(bf16x8*)&sAl[sr][sc + 8] = *(const bf16x8*)(pal + 8);
      *(bf16x8*)&sBh[sr][sc]     = *(const bf16x8*)pbh;
      *(bf16x8*)&sBh[sr][sc + 8] = *(const bf16x8*)(pbh + 8);
      *(bf16x8*)&sBl[sr][sc]     = *(const bf16x8*)pbl;
      *(bf16x8*)&sBl[sr][sc + 8] = *(const bf16x8*)(pbl + 8);
    }
    __syncthreads();
    bf16x8 afh[4], afl[4], bfh[4], bfl[4];
    #pragma unroll
    for (int i = 0; i < 4; ++i) {
      afh[i] = *(const bf16x8*)&sAh[wr * 64 + i * 16 + c][g * 8];
      afl[i] = *(const bf16x8*)&sAl[wr * 64 + i * 16 + c][g * 8];
      bfh[i] = *(const bf16x8*)&sBh[wc * 64 + i * 16 + c][g * 8];
      bfl[i] = *(const bf16x8*)&sBl[wc * 64 + i * 16 + c][g * 8];
    }
    #pragma unroll
    for (int i = 0; i < 4; ++i)
      #pragma unroll
      for (int j = 0; j < 4; ++j) {
        acc[i][j] = __builtin_amdgcn_mfma_f32_16x16x32_bf16(afh[i], bfh[j], acc[i][j], 0, 0, 0);
        acc[i][j] = __builtin_amdgcn_mfma_f32_16x16x32_bf16(afh[i], bfl[j], acc[i][j], 0, 0, 0);
        acc[i][j] = __builtin_amdgcn_mfma_f32_16x16x32_bf16(afl[i], bfh[j], acc[i][j], 0, 0, 0);
      }
  }
  #pragma unroll
  for (int i = 0; i < 4; ++i)
    #pragma unroll
    for (int j = 0; j < 4; ++j)
      #pragma unroll
      for (int rr = 0; rr < 4; ++rr) {
        int m = mb + wr * 64 + i * 16 + 4 * g + rr;
        int n = nb + wc * 64 + j * 16 + c;
        float v = (acc[i][j][rr] + bia[n]) * scale;
        unsigned short hh = f2bf(v);
        size_t idx = (size_t)m * 1024 + n;
        Ch[idx] = hh;
        Cl[idx] = f2bf(v - bf2f(hh));
      }
}

// ---------------- v projection, writes V^T layout: VT[b][e'][j] ----------------
__launch_bounds__(256, 2)
__global__ void k_proj_v(const unsigned short* __restrict__ wv, const unsigned short* __restrict__ vx,
                         const float* __restrict__ bias, unsigned short* __restrict__ VT) {
  __shared__ unsigned short sA[128][40], sB[128][40];
  const int t = threadIdx.x;
  const int wid = t >> 6, l = t & 63, g = l >> 4, c = l & 15;
  const int wr = wid >> 1, wc = wid & 1;
  const int mb = blockIdx.x * 128;   // e' base
  const int nb = blockIdx.y * 128;   // n = b*2048 + j
  const int bb = nb >> 11;
  const int jb = nb & 2047;
  const int sr = t >> 1, sc = (t & 1) * 16;

  f32x4 acc[4][4] = {};
  for (int k0 = 0; k0 < 1024; k0 += 32) {
    __syncthreads();
    {
      const unsigned short* pa = wv + (size_t)(mb + sr) * 1024 + k0 + sc;
      const unsigned short* pbp = vx + ((size_t)(jb + sr) * 2 + bb) * 1024 + k0 + sc;
      *(bf16x8*)&sA[sr][sc]     = *(const bf16x8*)pa;
      *(bf16x8*)&sA[sr][sc + 8] = *(const bf16x8*)(pa + 8);
      *(bf16x8*)&sB[sr][sc]     = *(const bf16x8*)pbp;
      *(bf16x8*)&sB[sr][sc + 8] = *(const bf16x8*)(pbp + 8);
    }
    __syncthreads();
    bf16x8 af[4], bfr[4];
    #pragma unroll
    for (int i = 0; i < 4; ++i) {
      af[i]  = *(const bf16x8*)&sA[wr * 64 + i * 16 + c][g * 8];
      bfr[i] = *(const bf16x8*)&sB[wc * 64 + i * 16 + c][g * 8];
    }
    #pragma unroll
    for (int i = 0; i < 4; ++i)
      #pragma unroll
      for (int j = 0; j < 4; ++j)
        acc[i][j] = __builtin_amdgcn_mfma_f32_16x16x32_bf16(af[i], bfr[j], acc[i][j], 0, 0, 0);
  }
  #pragma unroll
  for (int i = 0; i < 4; ++i)
    #pragma unroll
    for (int j = 0; j < 4; ++j)
      #pragma unroll
      for (int rr = 0; rr < 4; ++rr) {
        int m = mb + wr * 64 + i * 16 + 4 * g + rr;
        int jj = jb + wc * 64 + j * 16 + c;
        float v = acc[i][j][rr] + bias[2048 + m];
        VT[(size_t)bb * (1024 * 2048) + (size_t)m * 2048 + jj] = f2bf(v);
      }
}

// ---------------- attention: swapped QK^T + no-max softmax + bf16-packed p ----------------
// mfma(A=K-tile, B=Q) => acc at lane(g,c) holds s[k=tile*16+4g+rr][q=c].
// Per lane: one q-row, 128 k-values (32 tiles x 4). exp w/o max-subtract
// (|s| <= ~20 << 88), sum in-loop, p packed bf16x2 -> 64 u32 regs.
__launch_bounds__(256, 3)
__global__ void k_attn(const unsigned short* __restrict__ qh, const unsigned short* __restrict__ ql,
                       const unsigned short* __restrict__ kh, const unsigned short* __restrict__ kl,
                       const float* __restrict__ posb, float* __restrict__ attn) {
  const int bid = blockIdx.x;
  const int qt = bid & 127;
  const int h = (bid >> 7) & 15;
  const int b = bid >> 11;
  const int t = threadIdx.x;
  const int wid = t >> 6, l = t & 63, g = l >> 4, c = l & 15;

  const size_t qoff = ((size_t)(qt * 16 + c) * 2 + b) * 1024 + h * 64 + g * 8;
  const bf16x8 qfh0 = *(const bf16x8*)(qh + qoff);
  const bf16x8 qfh1 = *(const bf16x8*)(qh + qoff + 32);
  const bf16x8 qfl0 = *(const bf16x8*)(ql + qoff);
  const bf16x8 qfl1 = *(const bf16x8*)(ql + qoff + 32);

  const int jb0 = wid * 512;
  const float* pb = posb + (size_t)b * S_ * S_ + (size_t)(qt * 16 + c) * S_ + jb0;

  unsigned sc0[32], sc1[32];
  float lsum = 0.f;
  #pragma unroll
  for (int tt = 0; tt < 32; ++tt) {
    const size_t koff = ((size_t)(jb0 + tt * 16 + c) * 2 + b) * 1024 + h * 64 + g * 8;
    bf16x8 kfh0 = *(const bf16x8*)(kh + koff);
    bf16x8 kfh1 = *(const bf16x8*)(kh + koff + 32);
    bf16x8 kfl0 = *(const bf16x8*)(kl + koff);
    bf16x8 kfl1 = *(const bf16x8*)(kl + koff + 32);
    f32x4 bias4 = *(const f32x4*)(pb + tt * 16 + 4 * g);
    f32x4 acc = {};
    acc = __builtin_amdgcn_mfma_f32_16x16x32_bf16(kfh0, qfh0, acc, 0, 0, 0);
    acc = __builtin_amdgcn_mfma_f32_16x16x32_bf16(kfh1, qfh1, acc, 0, 0, 0);
    acc = __builtin_amdgcn_mfma_f32_16x16x32_bf16(kfl0, qfh0, acc, 0, 0, 0);
    acc = __builtin_amdgcn_mfma_f32_16x16x32_bf16(kfl1, qfh1, acc, 0, 0, 0);
    acc = __builtin_amdgcn_mfma_f32_16x16x32_bf16(kfh0, qfl0, acc, 0, 0, 0);
    acc = __builtin_amdgcn_mfma_f32_16x16x32_bf16(kfh1, qfl1, acc, 0, 0, 0);
    float p0 = __expf(acc[0] + bias4[0]);
    float p1 = __expf(acc[1] + bias4[1]);
    float p2 = __expf(acc[2] + bias4[2]);
    float p3 = __expf(acc[3] + bias4[3]);
    lsum += (p0 + p1) + (p2 + p3);
    sc0[tt] = pk_bf16(p0, p1);
    sc1[tt] = pk_bf16(p2, p3);
  }
  // reduce sum for q-row c: across g (lanes xor 16,32), then across 4 waves
  lsum += __shfl_xor(lsum, 16, 64);
  lsum += __shfl_xor(lsum, 32, 64);
  __shared__ float red[4][16];
  if (l < 16) red[wid][c] = lsum;
  __syncthreads();
  const float inv = 1.0f / (red[0][c] + red[1][c] + red[2][c] + red[3][c]);

  float* arow = attn + ((size_t)(b * 16 + h) * S_ + qt * 16 + c) * S_ + jb0;
  #pragma unroll
  for (int tt = 0; tt < 32; ++tt) {
    f32x4 o;
    o[0] = __uint_as_float(sc0[tt] << 16) * inv;
    o[1] = __uint_as_float(sc0[tt] & 0xFFFF0000u) * inv;
    o[2] = __uint_as_float(sc1[tt] << 16) * inv;
    o[3] = __uint_as_float(sc1[tt] & 0xFFFF0000u) * inv;
    *(f32x4*)(arow + tt * 16 + 4 * g) = o;
  }
}

// ---------------- PV: out_core = attn @ V  (reads attn f32, VT bf16) ----------------
__launch_bounds__(256, 2)
__global__ void k_pv(const float* __restrict__ attn, const unsigned short* __restrict__ VT,
                     unsigned short* __restrict__ oc) {
  __shared__ unsigned short sA[128][72];
  __shared__ unsigned short sB[64][72];
  const int t = threadIdx.x;
  const int wid = t >> 6, l = t & 63, g = l >> 4, c = l & 15;
  const int rb = blockIdx.x;
  const int bh = blockIdx.y;
  const int b = bh >> 4, h = bh & 15;
  const int rowb = rb * 128;
  const float* P = attn + (size_t)bh * S_ * S_;
  const unsigned short* Vp = VT + ((size_t)b * 1024 + h * 64) * 2048;

  f32x4 acc[2][4] = {};
  for (int k0 = 0; k0 < 2048; k0 += 64) {
    __syncthreads();
    #pragma unroll
    for (int it = 0; it < 8; ++it) {
      int idx = it * 1024 + t * 4;
      int r = idx >> 6, cc = idx & 63;
      f32x4 v = *(const f32x4*)(P + (size_t)(rowb + r) * S_ + k0 + cc);
      us4_t o;
      o[0] = f2bf(v[0]); o[1] = f2bf(v[1]); o[2] = f2bf(v[2]); o[3] = f2bf(v[3]);
      *(us4_t*)&sA[r][cc] = o;
    }
    #pragma unroll
    for (int it = 0; it < 2; ++it) {
      int idx = it * 2048 + t * 8;
      int r = idx >> 6, cc = idx & 63;
      *(bf16x8*)&sB[r][cc] = *(const bf16x8*)(Vp + (size_t)r * 2048 + k0 + cc);
    }
    __syncthreads();
    bf16x8 af[2][2], bfr[4][2];
    #pragma unroll
    for (int i = 0; i < 2; ++i)
      #pragma unroll
      for (int ck = 0; ck < 2; ++ck)
        af[i][ck] = *(const bf16x8*)&sA[wid * 32 + i * 16 + c][ck * 32 + g * 8];
    #pragma unroll
    for (int j = 0; j < 4; ++j)
      #pragma unroll
      for (int ck = 0; ck < 2; ++ck)
        bfr[j][ck] = *(const bf16x8*)&sB[j * 16 + c][ck * 32 + g * 8];
    #pragma unroll
    for (int i = 0; i < 2; ++i)
      #pragma unroll
      for (int j = 0; j < 4; ++j) {
        acc[i][j] = __builtin_amdgcn_mfma_f32_16x16x32_bf16(af[i][0], bfr[j][0], acc[i][j], 0, 0, 0);
        acc[i][j] = __builtin_amdgcn_mfma_f32_16x16x32_bf16(af[i][1], bfr[j][1], acc[i][j], 0, 0, 0);
      }
  }
  #pragma unroll
  for (int i = 0; i < 2; ++i)
    #pragma unroll
    for (int j = 0; j < 4; ++j)
      #pragma unroll
      for (int rr = 0; rr < 4; ++rr) {
        int row = rowb + wid * 32 + i * 16 + 4 * g + rr;
        int d = j * 16 + c;
        oc[((size_t)row * 2 + b) * 1024 + h * 64 + d] = f2bf(acc[i][j][rr]);
      }
}

// ---------------- out projection ----------------
__launch_bounds__(256, 2)
__global__ void k_outproj(const unsigned short* __restrict__ oc, const unsigned short* __restrict__ ow,
                          const float* __restrict__ ob, float* __restrict__ out) {
  __shared__ unsigned short sA[128][40], sB[128][40];
  const int t = threadIdx.x;
  const int wid = t >> 6, l = t & 63, g = l >> 4, c = l & 15;
  const int wr = wid >> 1, wc = wid & 1;
  const int mb = blockIdx.x * 128, nb = blockIdx.y * 128;
  const int sr = t >> 1, sc = (t & 1) * 16;

  f32x4 acc[4][4] = {};
  for (int k0 = 0; k0 < 1024; k0 += 32) {
    __syncthreads();
    {
      const unsigned short* pa = oc + (size_t)(mb + sr) * 1024 + k0 + sc;
      const unsigned short* pbp = ow + (size_t)(nb + sr) * 1024 + k0 + sc;
      *(bf16x8*)&sA[sr][sc]     = *(const bf16x8*)pa;
      *(bf16x8*)&sA[sr][sc + 8] = *(const bf16x8*)(pa + 8);
      *(bf16x8*)&sB[sr][sc]     = *(const bf16x8*)pbp;
      *(bf16x8*)&sB[sr][sc + 8] = *(const bf16x8*)(pbp + 8);
    }
    __syncthreads();
    bf16x8 af[4], bfr[4];
    #pragma unroll
    for (int i = 0; i < 4; ++i) {
      af[i]  = *(const bf16x8*)&sA[wr * 64 + i * 16 + c][g * 8];
      bfr[i] = *(const bf16x8*)&sB[wc * 64 + i * 16 + c][g * 8];
    }
    #pragma unroll
    for (int i = 0; i < 4; ++i)
      #pragma unroll
      for (int j = 0; j < 4; ++j)
        acc[i][j] = __builtin_amdgcn_mfma_f32_16x16x32_bf16(af[i], bfr[j], acc[i][j], 0, 0, 0);
  }
  #pragma unroll
  for (int i = 0; i < 4; ++i)
    #pragma unroll
    for (int j = 0; j < 4; ++j)
      #pragma unroll
      for (int rr = 0; rr < 4; ++rr) {
        int m = mb + wr * 64 + i * 16 + 4 * g + rr;
        int n = nb + wc * 64 + j * 16 + c;
        out[(size_t)m * 1024 + n] = acc[i][j][rr] + ob[n];
      }
}

extern "C" void kernel_launch(void* const* d_in, const int* in_sizes, int n_in,
                              void* d_out, int out_size, void* d_ws, size_t ws_size,
                              hipStream_t stream) {
  (void)in_sizes; (void)n_in; (void)out_size; (void)ws_size;
  const float* query = (const float*)d_in[0];
  const float* keyi  = (const float*)d_in[1];
  const float* value = (const float*)d_in[2];
  const float* posb  = (const float*)d_in[3];
  const float* ipw   = (const float*)d_in[4];
  const float* ipb   = (const float*)d_in[5];
  const float* outw  = (const float*)d_in[6];
  const float* outb  = (const float*)d_in[7];
  float* out = (float*)d_out;
  float* attn = out + (size_t)S_ * B_ * E_;

  char* ws = (char*)d_ws;
  size_t off = 0;
  auto alloc = [&](size_t bytes) -> void* {
    void* p = ws + off;
    off += (bytes + 255) & ~(size_t)255;
    return p;
  };
  const size_t NTOK = (size_t)S_ * B_;  // 4096
  unsigned short* qxh = (unsigned short*)alloc(NTOK * 1024 * 2);
  unsigned short* qxl = (unsigned short*)alloc(NTOK * 1024 * 2);
  unsigned short* kxh = (unsigned short*)alloc(NTOK * 1024 * 2);
  unsigned short* kxl = (unsigned short*)alloc(NTOK * 1024 * 2);
  unsigned short* vx  = (unsigned short*)alloc(NTOK * 1024 * 2);
  unsigned short* wh  = (unsigned short*)alloc((size_t)2048 * 1024 * 2);
  unsigned short* wl  = (unsigned short*)alloc((size_t)2048 * 1024 * 2);
  unsigned short* wv  = (unsigned short*)alloc((size_t)1024 * 1024 * 2);
  unsigned short* ow  = (unsigned short*)alloc((size_t)1024 * 1024 * 2);
  unsigned short* qh  = (unsigned short*)alloc(NTOK * 1024 * 2);
  unsigned short* ql  = (unsigned short*)alloc(NTOK * 1024 * 2);
  unsigned short* kh  = (unsigned short*)alloc(NTOK * 1024 * 2);
  unsigned short* kl  = (unsigned short*)alloc(NTOK * 1024 * 2);
  unsigned short* VT  = (unsigned short*)alloc((size_t)2 * 1024 * 2048 * 2);
  unsigned short* oc  = (unsigned short*)alloc(NTOK * 1024 * 2);

  const int n1_4 = (int)(NTOK * 1024 / 4);  // 1048576 vec4 elems
  k_split2<<<2048, 256, 0, stream>>>(query, qxh, qxl, n1_4);
  k_split2<<<2048, 256, 0, stream>>>(keyi, kxh, kxl, n1_4);
  k_cvt<<<2048, 256, 0, stream>>>(value, vx, n1_4);
  k_split2<<<1024, 256, 0, stream>>>(ipw, wh, wl, 2048 * 1024 / 4);
  k_cvt<<<512, 256, 0, stream>>>(ipw + 2048 * 1024, wv, 1024 * 1024 / 4);
  k_cvt<<<512, 256, 0, stream>>>(outw, ow, 1024 * 1024 / 4);

  k_proj_qk<<<dim3(32, 8, 2), 256, 0, stream>>>(qxh, qxl, kxh, kxl, wh, wl, ipb, qh, ql, kh, kl);
  k_proj_v<<<dim3(8, 32), 256, 0, stream>>>(wv, vx, ipb, VT);
  k_attn<<<4096, 256, 0, stream>>>(qh, ql, kh, kl, posb, attn);
  k_pv<<<dim3(16, 32), 256, 0, stream>>>(attn, VT, oc);
  k_outproj<<<dim3(32, 8), 256, 0, stream>>>(oc, ow, outb, out);
}

// Round 4
// 632.813 us; speedup vs baseline: 1.2344x; 1.0652x over previous
//
#include <hip/hip_runtime.h>

#define S_ 2048
#define B_ 2
#define E_ 1024
#define H_ 16

typedef __bf16 bf16x8 __attribute__((ext_vector_type(8)));
typedef float f32x4 __attribute__((ext_vector_type(4)));
typedef unsigned short us4_t __attribute__((ext_vector_type(4)));

static __device__ __forceinline__ unsigned short f2bf(float x) {
  union { float f; unsigned u; } v; v.f = x;
  unsigned r = v.u + 0x7fffu + ((v.u >> 16) & 1u);
  return (unsigned short)(r >> 16);
}
static __device__ __forceinline__ float bf2f(unsigned short h) {
  union { unsigned u; float f; } v; v.u = ((unsigned)h) << 16;
  return v.f;
}
static __device__ __forceinline__ unsigned pk_bf16(float a, float b) {
  // dst.lo = bf16(a), dst.hi = bf16(b)
  unsigned r;
  asm("v_cvt_pk_bf16_f32 %0, %1, %2" : "=v"(r) : "v"(a), "v"(b));
  return r;
}

// ---------------- elementwise split / convert (vectorized) ----------------
__global__ void k_split2(const float* __restrict__ src, unsigned short* __restrict__ hi,
                         unsigned short* __restrict__ lo, int n4) {
  int i = blockIdx.x * blockDim.x + threadIdx.x;
  int st = gridDim.x * blockDim.x;
  for (; i < n4; i += st) {
    f32x4 x = ((const f32x4*)src)[i];
    us4_t h, lw;
    #pragma unroll
    for (int j = 0; j < 4; ++j) {
      unsigned short hh = f2bf(x[j]);
      h[j] = hh;
      lw[j] = f2bf(x[j] - bf2f(hh));
    }
    ((us4_t*)hi)[i] = h;
    ((us4_t*)lo)[i] = lw;
  }
}

__global__ void k_cvt(const float* __restrict__ src, unsigned short* __restrict__ dst, int n4) {
  int i = blockIdx.x * blockDim.x + threadIdx.x;
  int st = gridDim.x * blockDim.x;
  for (; i < n4; i += st) {
    f32x4 x = ((const f32x4*)src)[i];
    us4_t h;
    #pragma unroll
    for (int j = 0; j < 4; ++j) h[j] = f2bf(x[j]);
    ((us4_t*)dst)[i] = h;
  }
}

// ---------------- q/k projection: 3-term split GEMM ----------------
__launch_bounds__(256, 2)
__global__ void k_proj_qk(const unsigned short* __restrict__ qxh, const unsigned short* __restrict__ qxl,
                          const unsigned short* __restrict__ kxh, const unsigned short* __restrict__ kxl,
                          const unsigned short* __restrict__ wh, const unsigned short* __restrict__ wl,
                          const float* __restrict__ bias,
                          unsigned short* __restrict__ qh, unsigned short* __restrict__ ql,
                          unsigned short* __restrict__ kh, unsigned short* __restrict__ kl) {
  const int z = blockIdx.z;
  const unsigned short* Ah = z ? kxh : qxh;
  const unsigned short* Al = z ? kxl : qxl;
  const unsigned short* Bh = wh + (size_t)z * (1024 * 1024);
  const unsigned short* Bl = wl + (size_t)z * (1024 * 1024);
  unsigned short* Ch = z ? kh : qh;
  unsigned short* Cl = z ? kl : ql;
  const float* bia = bias + z * 1024;
  const float scale = z ? 1.0f : 0.125f;

  __shared__ unsigned short sAh[128][40], sAl[128][40], sBh[128][40], sBl[128][40];

  const int t = threadIdx.x;
  const int wid = t >> 6, l = t & 63, g = l >> 4, c = l & 15;
  const int wr = wid >> 1, wc = wid & 1;
  const int mb = blockIdx.x * 128, nb = blockIdx.y * 128;
  const int sr = t >> 1, sc = (t & 1) * 16;

  f32x4 acc[4][4] = {};

  for (int k0 = 0; k0 < 1024; k0 += 32) {
    __syncthreads();
    {
      const unsigned short* pah = Ah + (size_t)(mb + sr) * 1024 + k0 + sc;
      const unsigned short* pal = Al + (size_t)(mb + sr) * 1024 + k0 + sc;
      const unsigned short* pbh = Bh + (size_t)(nb + sr) * 1024 + k0 + sc;
      const unsigned short* pbl = Bl + (size_t)(nb + sr) * 1024 + k0 + sc;
      *(bf16x8*)&sAh[sr][sc]     = *(const bf16x8*)pah;
      *(bf16x8*)&sAh[sr][sc + 8] = *(const bf16x8*)(pah + 8);
      *(bf16x8*)&sAl[sr][sc]     = *(const bf16x8*)pal;
      *(bf16x8*)&sAl[sr][sc + 8] = *(const bf16x8*)(pal + 8);
      *(bf16x8*)&sBh[sr][sc]     = *(const bf16x8*)pbh;
      *(bf16x8*)&sBh[sr][sc + 8] = *(const bf16x8*)(pbh + 8);
      *(bf16x8*)&sBl[sr][sc]     = *(const bf16x8*)pbl;
      *(bf16x8*)&sBl[sr][sc + 8] = *(const bf16x8*)(pbl + 8);
    }
    __syncthreads();
    bf16x8 afh[4], afl[4], bfh[4], bfl[4];
    #pragma unroll
    for (int i = 0; i < 4; ++i) {
      afh[i] = *(const bf16x8*)&sAh[wr * 64 + i * 16 + c][g * 8];
      afl[i] = *(const bf16x8*)&sAl[wr * 64 + i * 16 + c][g * 8];
      bfh[i] = *(const bf16x8*)&sBh[wc * 64 + i * 16 + c][g * 8];
      bfl[i] = *(const bf16x8*)&sBl[wc * 64 + i * 16 + c][g * 8];
    }
    #pragma unroll
    for (int i = 0; i < 4; ++i)
      #pragma unroll
      for (int j = 0; j < 4; ++j) {
        acc[i][j] = __builtin_amdgcn_mfma_f32_16x16x32_bf16(afh[i], bfh[j], acc[i][j], 0, 0, 0);
        acc[i][j] = __builtin_amdgcn_mfma_f32_16x16x32_bf16(afh[i], bfl[j], acc[i][j], 0, 0, 0);
        acc[i][j] = __builtin_amdgcn_mfma_f32_16x16x32_bf16(afl[i], bfh[j], acc[i][j], 0, 0, 0);
      }
  }
  #pragma unroll
  for (int i = 0; i < 4; ++i)
    #pragma unroll
    for (int j = 0; j < 4; ++j)
      #pragma unroll
      for (int rr = 0; rr < 4; ++rr) {
        int m = mb + wr * 64 + i * 16 + 4 * g + rr;
        int n = nb + wc * 64 + j * 16 + c;
        float v = (acc[i][j][rr] + bia[n]) * scale;
        unsigned short hh = f2bf(v);
        size_t idx = (size_t)m * 1024 + n;
        Ch[idx] = hh;
        Cl[idx] = f2bf(v - bf2f(hh));
      }
}

// ---------------- v projection, writes V^T layout: VT[b][e'][j] ----------------
__launch_bounds__(256, 2)
__global__ void k_proj_v(const unsigned short* __restrict__ wv, const unsigned short* __restrict__ vx,
                         const float* __restrict__ bias, unsigned short* __restrict__ VT) {
  __shared__ unsigned short sA[128][40], sB[128][40];
  const int t = threadIdx.x;
  const int wid = t >> 6, l = t & 63, g = l >> 4, c = l & 15;
  const int wr = wid >> 1, wc = wid & 1;
  const int mb = blockIdx.x * 128;   // e' base
  const int nb = blockIdx.y * 128;   // n = b*2048 + j
  const int bb = nb >> 11;
  const int jb = nb & 2047;
  const int sr = t >> 1, sc = (t & 1) * 16;

  f32x4 acc[4][4] = {};
  for (int k0 = 0; k0 < 1024; k0 += 32) {
    __syncthreads();
    {
      const unsigned short* pa = wv + (size_t)(mb + sr) * 1024 + k0 + sc;
      const unsigned short* pbp = vx + ((size_t)(jb + sr) * 2 + bb) * 1024 + k0 + sc;
      *(bf16x8*)&sA[sr][sc]     = *(const bf16x8*)pa;
      *(bf16x8*)&sA[sr][sc + 8] = *(const bf16x8*)(pa + 8);
      *(bf16x8*)&sB[sr][sc]     = *(const bf16x8*)pbp;
      *(bf16x8*)&sB[sr][sc + 8] = *(const bf16x8*)(pbp + 8);
    }
    __syncthreads();
    bf16x8 af[4], bfr[4];
    #pragma unroll
    for (int i = 0; i < 4; ++i) {
      af[i]  = *(const bf16x8*)&sA[wr * 64 + i * 16 + c][g * 8];
      bfr[i] = *(const bf16x8*)&sB[wc * 64 + i * 16 + c][g * 8];
    }
    #pragma unroll
    for (int i = 0; i < 4; ++i)
      #pragma unroll
      for (int j = 0; j < 4; ++j)
        acc[i][j] = __builtin_amdgcn_mfma_f32_16x16x32_bf16(af[i], bfr[j], acc[i][j], 0, 0, 0);
  }
  #pragma unroll
  for (int i = 0; i < 4; ++i)
    #pragma unroll
    for (int j = 0; j < 4; ++j)
      #pragma unroll
      for (int rr = 0; rr < 4; ++rr) {
        int m = mb + wr * 64 + i * 16 + 4 * g + rr;
        int jj = jb + wc * 64 + j * 16 + c;
        float v = acc[i][j][rr] + bias[2048 + m];
        VT[(size_t)bb * (1024 * 2048) + (size_t)m * 2048 + jj] = f2bf(v);
      }
}

// ---------------- fused attention: QK^T + softmax + attn-write + PV ----------------
// 512 threads = 8 waves; wave w owns cols [w*256, w*256+256).
// Swapped QK: acc[rr]@lane(g,c) = s[k=tile*16+4g+rr][q=c]. p packed bf16 pairs.
// PV per 32-k step: per-wave LDS ping reshapes p into MFMA B-operand (P^T);
// A-operand = V^T frags from VT. Cross-wave out reduce in LDS -> oc.
__launch_bounds__(512, 3)
__global__ void k_attn_pv(const unsigned short* __restrict__ qh, const unsigned short* __restrict__ ql,
                          const unsigned short* __restrict__ kh, const unsigned short* __restrict__ kl,
                          const unsigned short* __restrict__ VT, const float* __restrict__ posb,
                          float* __restrict__ attn, unsigned short* __restrict__ oc) {
  // XCD swizzle: 128 consecutive logical blocks share one (b,h) K/V slice.
  const int bid = (int)((blockIdx.x & 7) * 512 + (blockIdx.x >> 3));
  const int qt = bid & 127;
  const int h = (bid >> 7) & 15;
  const int b = bid >> 11;
  const int t = threadIdx.x;
  const int wid = t >> 6, l = t & 63, g = l >> 4, c = l & 15;
  const int jb0 = wid * 256;

  __shared__ unsigned pvbuf[8 * 640];     // per-wave 2x320 u32 ping (pad 20)
  __shared__ float red[8][16];
  __shared__ float ored[8][16][64];       // [wave][q][d] partial out

  const size_t qoff = ((size_t)(qt * 16 + c) * 2 + b) * 1024 + h * 64 + g * 8;
  const bf16x8 qfh0 = *(const bf16x8*)(qh + qoff);
  const bf16x8 qfh1 = *(const bf16x8*)(qh + qoff + 32);
  const bf16x8 qfl0 = *(const bf16x8*)(ql + qoff);
  const bf16x8 qfl1 = *(const bf16x8*)(ql + qoff + 32);

  const float* pb = posb + (size_t)b * S_ * S_ + (size_t)(qt * 16 + c) * S_ + jb0;
  const unsigned short* Vbase = VT + ((size_t)b * 1024 + h * 64) * 2048;
  unsigned* myping = &pvbuf[wid * 640];

  unsigned psc0[16], psc1[16];
  float lsum = 0.f;
  f32x4 oacc[4] = {};

  #pragma unroll
  for (int st = 0; st < 8; ++st) {
    #pragma unroll
    for (int th = 0; th < 2; ++th) {
      const int tt = st * 2 + th;
      const size_t koff = ((size_t)(jb0 + tt * 16 + c) * 2 + b) * 1024 + h * 64 + g * 8;
      bf16x8 kfh0 = *(const bf16x8*)(kh + koff);
      bf16x8 kfh1 = *(const bf16x8*)(kh + koff + 32);
      bf16x8 kfl0 = *(const bf16x8*)(kl + koff);
      bf16x8 kfl1 = *(const bf16x8*)(kl + koff + 32);
      f32x4 bias4 = *(const f32x4*)(pb + tt * 16 + 4 * g);
      f32x4 acc = {};
      acc = __builtin_amdgcn_mfma_f32_16x16x32_bf16(kfh0, qfh0, acc, 0, 0, 0);
      acc = __builtin_amdgcn_mfma_f32_16x16x32_bf16(kfh1, qfh1, acc, 0, 0, 0);
      acc = __builtin_amdgcn_mfma_f32_16x16x32_bf16(kfl0, qfh0, acc, 0, 0, 0);
      acc = __builtin_amdgcn_mfma_f32_16x16x32_bf16(kfl1, qfh1, acc, 0, 0, 0);
      acc = __builtin_amdgcn_mfma_f32_16x16x32_bf16(kfh0, qfl0, acc, 0, 0, 0);
      acc = __builtin_amdgcn_mfma_f32_16x16x32_bf16(kfh1, qfl1, acc, 0, 0, 0);
      float p0 = __expf(acc[0] + bias4[0]);
      float p1 = __expf(acc[1] + bias4[1]);
      float p2 = __expf(acc[2] + bias4[2]);
      float p3 = __expf(acc[3] + bias4[3]);
      lsum += (p0 + p1) + (p2 + p3);
      psc0[tt] = pk_bf16(p0, p1);
      psc1[tt] = pk_bf16(p2, p3);
    }
    // ---- PV for this 32-k step ----
    unsigned* pg = myping + (st & 1) * 320;
    // store slots: idx = c*20 + th*8 + 2g -> pair (sc0, sc1)
    *(unsigned long long*)&pg[c * 20 + 2 * g] =
        (unsigned long long)psc0[st * 2] | ((unsigned long long)psc1[st * 2] << 32);
    *(unsigned long long*)&pg[c * 20 + 8 + 2 * g] =
        (unsigned long long)psc0[st * 2 + 1] | ((unsigned long long)psc1[st * 2 + 1] << 32);
    // compiler-level fence: forbid reordering the aliased LDS read above the writes
    asm volatile("" ::: "memory");
    // read B-frag (P^T): k = 8g..8g+7, q = c
    bf16x8 bfrag = *(bf16x8*)&pg[c * 20 + 4 * g];
    #pragma unroll
    for (int dtile = 0; dtile < 4; ++dtile) {
      bf16x8 vfrag = *(const bf16x8*)(Vbase + (size_t)(dtile * 16 + c) * 2048 + jb0 + st * 32 + g * 8);
      oacc[dtile] = __builtin_amdgcn_mfma_f32_16x16x32_bf16(vfrag, bfrag, oacc[dtile], 0, 0, 0);
    }
  }

  // softmax denominator across g within wave, then across 8 waves
  lsum += __shfl_xor(lsum, 16, 64);
  lsum += __shfl_xor(lsum, 32, 64);
  if (l < 16) red[wid][l] = lsum;
  __syncthreads();
  const float inv = 1.0f / (((red[0][c] + red[1][c]) + (red[2][c] + red[3][c])) +
                            ((red[4][c] + red[5][c]) + (red[6][c] + red[7][c])));

  // scaled partial out -> LDS
  #pragma unroll
  for (int dtile = 0; dtile < 4; ++dtile) {
    f32x4 o = oacc[dtile];
    o[0] *= inv; o[1] *= inv; o[2] *= inv; o[3] *= inv;
    *(f32x4*)&ored[wid][c][dtile * 16 + 4 * g] = o;
  }
  __syncthreads();

  // cross-wave reduce (1024 outputs, 2 per thread) -> oc (bf16)
  {
    const int q = t >> 5;
    const int d = (t & 31) * 2;
    float s0 = 0.f, s1 = 0.f;
    #pragma unroll
    for (int w = 0; w < 8; ++w) { s0 += ored[w][q][d]; s1 += ored[w][q][d + 1]; }
    unsigned pk = pk_bf16(s0, s1);
    *(unsigned*)&oc[((size_t)(qt * 16 + q) * 2 + b) * 1024 + h * 64 + d] = pk;
  }

  // attn write (normalized), 16B per lane per tile
  float* arow = attn + ((size_t)(b * 16 + h) * S_ + qt * 16 + c) * S_ + jb0;
  #pragma unroll
  for (int tt = 0; tt < 16; ++tt) {
    f32x4 o;
    o[0] = __uint_as_float(psc0[tt] << 16) * inv;
    o[1] = __uint_as_float(psc0[tt] & 0xFFFF0000u) * inv;
    o[2] = __uint_as_float(psc1[tt] << 16) * inv;
    o[3] = __uint_as_float(psc1[tt] & 0xFFFF0000u) * inv;
    *(f32x4*)(arow + tt * 16 + 4 * g) = o;
  }
}

// ---------------- out projection ----------------
__launch_bounds__(256, 2)
__global__ void k_outproj(const unsigned short* __restrict__ oc, const unsigned short* __restrict__ ow,
                          const float* __restrict__ ob, float* __restrict__ out) {
  __shared__ unsigned short sA[128][40], sB[128][40];
  const int t = threadIdx.x;
  const int wid = t >> 6, l = t & 63, g = l >> 4, c = l & 15;
  const int wr = wid >> 1, wc = wid & 1;
  const int mb = blockIdx.x * 128, nb = blockIdx.y * 128;
  const int sr = t >> 1, sc = (t & 1) * 16;

  f32x4 acc[4][4] = {};
  for (int k0 = 0; k0 < 1024; k0 += 32) {
    __syncthreads();
    {
      const unsigned short* pa = oc + (size_t)(mb + sr) * 1024 + k0 + sc;
      const unsigned short* pbp = ow + (size_t)(nb + sr) * 1024 + k0 + sc;
      *(bf16x8*)&sA[sr][sc]     = *(const bf16x8*)pa;
      *(bf16x8*)&sA[sr][sc + 8] = *(const bf16x8*)(pa + 8);
      *(bf16x8*)&sB[sr][sc]     = *(const bf16x8*)pbp;
      *(bf16x8*)&sB[sr][sc + 8] = *(const bf16x8*)(pbp + 8);
    }
    __syncthreads();
    bf16x8 af[4], bfr[4];
    #pragma unroll
    for (int i = 0; i < 4; ++i) {
      af[i]  = *(const bf16x8*)&sA[wr * 64 + i * 16 + c][g * 8];
      bfr[i] = *(const bf16x8*)&sB[wc * 64 + i * 16 + c][g * 8];
    }
    #pragma unroll
    for (int i = 0; i < 4; ++i)
      #pragma unroll
      for (int j = 0; j < 4; ++j)
        acc[i][j] = __builtin_amdgcn_mfma_f32_16x16x32_bf16(af[i], bfr[j], acc[i][j], 0, 0, 0);
  }
  #pragma unroll
  for (int i = 0; i < 4; ++i)
    #pragma unroll
    for (int j = 0; j < 4; ++j)
      #pragma unroll
      for (int rr = 0; rr < 4; ++rr) {
        int m = mb + wr * 64 + i * 16 + 4 * g + rr;
        int n = nb + wc * 64 + j * 16 + c;
        out[(size_t)m * 1024 + n] = acc[i][j][rr] + ob[n];
      }
}

extern "C" void kernel_launch(void* const* d_in, const int* in_sizes, int n_in,
                              void* d_out, int out_size, void* d_ws, size_t ws_size,
                              hipStream_t stream) {
  (void)in_sizes; (void)n_in; (void)out_size; (void)ws_size;
  const float* query = (const float*)d_in[0];
  const float* keyi  = (const float*)d_in[1];
  const float* value = (const float*)d_in[2];
  const float* posb  = (const float*)d_in[3];
  const float* ipw   = (const float*)d_in[4];
  const float* ipb   = (const float*)d_in[5];
  const float* outw  = (const float*)d_in[6];
  const float* outb  = (const float*)d_in[7];
  float* out = (float*)d_out;
  float* attn = out + (size_t)S_ * B_ * E_;

  char* ws = (char*)d_ws;
  size_t off = 0;
  auto alloc = [&](size_t bytes) -> void* {
    void* p = ws + off;
    off += (bytes + 255) & ~(size_t)255;
    return p;
  };
  const size_t NTOK = (size_t)S_ * B_;  // 4096
  unsigned short* qxh = (unsigned short*)alloc(NTOK * 1024 * 2);
  unsigned short* qxl = (unsigned short*)alloc(NTOK * 1024 * 2);
  unsigned short* kxh = (unsigned short*)alloc(NTOK * 1024 * 2);
  unsigned short* kxl = (unsigned short*)alloc(NTOK * 1024 * 2);
  unsigned short* vx  = (unsigned short*)alloc(NTOK * 1024 * 2);
  unsigned short* wh  = (unsigned short*)alloc((size_t)2048 * 1024 * 2);
  unsigned short* wl  = (unsigned short*)alloc((size_t)2048 * 1024 * 2);
  unsigned short* wv  = (unsigned short*)alloc((size_t)1024 * 1024 * 2);
  unsigned short* ow  = (unsigned short*)alloc((size_t)1024 * 1024 * 2);
  unsigned short* qh  = (unsigned short*)alloc(NTOK * 1024 * 2);
  unsigned short* ql  = (unsigned short*)alloc(NTOK * 1024 * 2);
  unsigned short* kh  = (unsigned short*)alloc(NTOK * 1024 * 2);
  unsigned short* kl  = (unsigned short*)alloc(NTOK * 1024 * 2);
  unsigned short* VT  = (unsigned short*)alloc((size_t)2 * 1024 * 2048 * 2);
  unsigned short* oc  = (unsigned short*)alloc(NTOK * 1024 * 2);

  const int n1_4 = (int)(NTOK * 1024 / 4);
  k_split2<<<2048, 256, 0, stream>>>(query, qxh, qxl, n1_4);
  k_split2<<<2048, 256, 0, stream>>>(keyi, kxh, kxl, n1_4);
  k_cvt<<<2048, 256, 0, stream>>>(value, vx, n1_4);
  k_split2<<<1024, 256, 0, stream>>>(ipw, wh, wl, 2048 * 1024 / 4);
  k_cvt<<<512, 256, 0, stream>>>(ipw + 2048 * 1024, wv, 1024 * 1024 / 4);
  k_cvt<<<512, 256, 0, stream>>>(outw, ow, 1024 * 1024 / 4);

  k_proj_qk<<<dim3(32, 8, 2), 256, 0, stream>>>(qxh, qxl, kxh, kxl, wh, wl, ipb, qh, ql, kh, kl);
  k_proj_v<<<dim3(8, 32), 256, 0, stream>>>(wv, vx, ipb, VT);
  k_attn_pv<<<4096, 512, 0, stream>>>(qh, ql, kh, kl, VT, posb, attn, oc);
  k_outproj<<<dim3(32, 8), 256, 0, stream>>>(oc, ow, outb, out);
}

// Round 5
// 620.547 us; speedup vs baseline: 1.2588x; 1.0198x over previous
//
#include <hip/hip_runtime.h>

#define S_ 2048
#define B_ 2
#define E_ 1024
#define H_ 16

typedef __bf16 bf16x8 __attribute__((ext_vector_type(8)));
typedef float f32x4 __attribute__((ext_vector_type(4)));
typedef unsigned short us4_t __attribute__((ext_vector_type(4)));
typedef unsigned u32x4 __attribute__((ext_vector_type(4)));

static __device__ __forceinline__ unsigned short f2bf(float x) {
  union { float f; unsigned u; } v; v.f = x;
  unsigned r = v.u + 0x7fffu + ((v.u >> 16) & 1u);
  return (unsigned short)(r >> 16);
}
static __device__ __forceinline__ float bf2f(unsigned short h) {
  union { unsigned u; float f; } v; v.u = ((unsigned)h) << 16;
  return v.f;
}
static __device__ __forceinline__ unsigned pk_bf16(float a, float b) {
  // dst.lo = bf16(a), dst.hi = bf16(b)
  unsigned r;
  asm("v_cvt_pk_bf16_f32 %0, %1, %2" : "=v"(r) : "v"(a), "v"(b));
  return r;
}

// ---------------- elementwise split / convert (vectorized) ----------------
__global__ void k_split2(const float* __restrict__ src, unsigned short* __restrict__ hi,
                         unsigned short* __restrict__ lo, int n4) {
  int i = blockIdx.x * blockDim.x + threadIdx.x;
  int st = gridDim.x * blockDim.x;
  for (; i < n4; i += st) {
    f32x4 x = ((const f32x4*)src)[i];
    us4_t h, lw;
    #pragma unroll
    for (int j = 0; j < 4; ++j) {
      unsigned short hh = f2bf(x[j]);
      h[j] = hh;
      lw[j] = f2bf(x[j] - bf2f(hh));
    }
    ((us4_t*)hi)[i] = h;
    ((us4_t*)lo)[i] = lw;
  }
}

__global__ void k_cvt(const float* __restrict__ src, unsigned short* __restrict__ dst, int n4) {
  int i = blockIdx.x * blockDim.x + threadIdx.x;
  int st = gridDim.x * blockDim.x;
  for (; i < n4; i += st) {
    f32x4 x = ((const f32x4*)src)[i];
    us4_t h;
    #pragma unroll
    for (int j = 0; j < 4; ++j) h[j] = f2bf(x[j]);
    ((us4_t*)dst)[i] = h;
  }
}

// ---------------- q/k projection: 3-term split GEMM ----------------
__launch_bounds__(256, 2)
__global__ void k_proj_qk(const unsigned short* __restrict__ qxh, const unsigned short* __restrict__ qxl,
                          const unsigned short* __restrict__ kxh, const unsigned short* __restrict__ kxl,
                          const unsigned short* __restrict__ wh, const unsigned short* __restrict__ wl,
                          const float* __restrict__ bias,
                          unsigned short* __restrict__ qh, unsigned short* __restrict__ ql,
                          unsigned short* __restrict__ kh, unsigned short* __restrict__ kl) {
  const int z = blockIdx.z;
  const unsigned short* Ah = z ? kxh : qxh;
  const unsigned short* Al = z ? kxl : qxl;
  const unsigned short* Bh = wh + (size_t)z * (1024 * 1024);
  const unsigned short* Bl = wl + (size_t)z * (1024 * 1024);
  unsigned short* Ch = z ? kh : qh;
  unsigned short* Cl = z ? kl : ql;
  const float* bia = bias + z * 1024;
  const float scale = z ? 1.0f : 0.125f;

  __shared__ unsigned short sAh[128][40], sAl[128][40], sBh[128][40], sBl[128][40];

  const int t = threadIdx.x;
  const int wid = t >> 6, l = t & 63, g = l >> 4, c = l & 15;
  const int wr = wid >> 1, wc = wid & 1;
  const int mb = blockIdx.x * 128, nb = blockIdx.y * 128;
  const int sr = t >> 1, sc = (t & 1) * 16;

  f32x4 acc[4][4] = {};

  for (int k0 = 0; k0 < 1024; k0 += 32) {
    __syncthreads();
    {
      const unsigned short* pah = Ah + (size_t)(mb + sr) * 1024 + k0 + sc;
      const unsigned short* pal = Al + (size_t)(mb + sr) * 1024 + k0 + sc;
      const unsigned short* pbh = Bh + (size_t)(nb + sr) * 1024 + k0 + sc;
      const unsigned short* pbl = Bl + (size_t)(nb + sr) * 1024 + k0 + sc;
      *(bf16x8*)&sAh[sr][sc]     = *(const bf16x8*)pah;
      *(bf16x8*)&sAh[sr][sc + 8] = *(const bf16x8*)(pah + 8);
      *(bf16x8*)&sAl[sr][sc]     = *(const bf16x8*)pal;
      *(bf16x8*)&sAl[sr][sc + 8] = *(const bf16x8*)(pal + 8);
      *(bf16x8*)&sBh[sr][sc]     = *(const bf16x8*)pbh;
      *(bf16x8*)&sBh[sr][sc + 8] = *(const bf16x8*)(pbh + 8);
      *(bf16x8*)&sBl[sr][sc]     = *(const bf16x8*)pbl;
      *(bf16x8*)&sBl[sr][sc + 8] = *(const bf16x8*)(pbl + 8);
    }
    __syncthreads();
    bf16x8 afh[4], afl[4], bfh[4], bfl[4];
    #pragma unroll
    for (int i = 0; i < 4; ++i) {
      afh[i] = *(const bf16x8*)&sAh[wr * 64 + i * 16 + c][g * 8];
      afl[i] = *(const bf16x8*)&sAl[wr * 64 + i * 16 + c][g * 8];
      bfh[i] = *(const bf16x8*)&sBh[wc * 64 + i * 16 + c][g * 8];
      bfl[i] = *(const bf16x8*)&sBl[wc * 64 + i * 16 + c][g * 8];
    }
    #pragma unroll
    for (int i = 0; i < 4; ++i)
      #pragma unroll
      for (int j = 0; j < 4; ++j) {
        acc[i][j] = __builtin_amdgcn_mfma_f32_16x16x32_bf16(afh[i], bfh[j], acc[i][j], 0, 0, 0);
        acc[i][j] = __builtin_amdgcn_mfma_f32_16x16x32_bf16(afh[i], bfl[j], acc[i][j], 0, 0, 0);
        acc[i][j] = __builtin_amdgcn_mfma_f32_16x16x32_bf16(afl[i], bfh[j], acc[i][j], 0, 0, 0);
      }
  }
  #pragma unroll
  for (int i = 0; i < 4; ++i)
    #pragma unroll
    for (int j = 0; j < 4; ++j)
      #pragma unroll
      for (int rr = 0; rr < 4; ++rr) {
        int m = mb + wr * 64 + i * 16 + 4 * g + rr;
        int n = nb + wc * 64 + j * 16 + c;
        float v = (acc[i][j][rr] + bia[n]) * scale;
        unsigned short hh = f2bf(v);
        size_t idx = (size_t)m * 1024 + n;
        Ch[idx] = hh;
        Cl[idx] = f2bf(v - bf2f(hh));
      }
}

// ---------------- v projection, writes V^T layout: VT[b][e'][j] ----------------
__launch_bounds__(256, 2)
__global__ void k_proj_v(const unsigned short* __restrict__ wv, const unsigned short* __restrict__ vx,
                         const float* __restrict__ bias, unsigned short* __restrict__ VT) {
  __shared__ unsigned short sA[128][40], sB[128][40];
  const int t = threadIdx.x;
  const int wid = t >> 6, l = t & 63, g = l >> 4, c = l & 15;
  const int wr = wid >> 1, wc = wid & 1;
  const int mb = blockIdx.x * 128;   // e' base
  const int nb = blockIdx.y * 128;   // n = b*2048 + j
  const int bb = nb >> 11;
  const int jb = nb & 2047;
  const int sr = t >> 1, sc = (t & 1) * 16;

  f32x4 acc[4][4] = {};
  for (int k0 = 0; k0 < 1024; k0 += 32) {
    __syncthreads();
    {
      const unsigned short* pa = wv + (size_t)(mb + sr) * 1024 + k0 + sc;
      const unsigned short* pbp = vx + ((size_t)(jb + sr) * 2 + bb) * 1024 + k0 + sc;
      *(bf16x8*)&sA[sr][sc]     = *(const bf16x8*)pa;
      *(bf16x8*)&sA[sr][sc + 8] = *(const bf16x8*)(pa + 8);
      *(bf16x8*)&sB[sr][sc]     = *(const bf16x8*)pbp;
      *(bf16x8*)&sB[sr][sc + 8] = *(const bf16x8*)(pbp + 8);
    }
    __syncthreads();
    bf16x8 af[4], bfr[4];
    #pragma unroll
    for (int i = 0; i < 4; ++i) {
      af[i]  = *(const bf16x8*)&sA[wr * 64 + i * 16 + c][g * 8];
      bfr[i] = *(const bf16x8*)&sB[wc * 64 + i * 16 + c][g * 8];
    }
    #pragma unroll
    for (int i = 0; i < 4; ++i)
      #pragma unroll
      for (int j = 0; j < 4; ++j)
        acc[i][j] = __builtin_amdgcn_mfma_f32_16x16x32_bf16(af[i], bfr[j], acc[i][j], 0, 0, 0);
  }
  #pragma unroll
  for (int i = 0; i < 4; ++i)
    #pragma unroll
    for (int j = 0; j < 4; ++j)
      #pragma unroll
      for (int rr = 0; rr < 4; ++rr) {
        int m = mb + wr * 64 + i * 16 + 4 * g + rr;
        int jj = jb + wc * 64 + j * 16 + c;
        float v = acc[i][j][rr] + bias[2048 + m];
        VT[(size_t)bb * (1024 * 2048) + (size_t)m * 2048 + jj] = f2bf(v);
      }
}

// ---------------- fused attention: QK^T + softmax + attn-write + PV ----------------
// 512 threads = 8 waves; wave w owns cols [w*256, w*256+256).
// Swapped QK: acc[rr]@lane(g,c) = s[k=tile*16+4g+rr][q=c]. p packed bf16 pairs.
// PV per 32-k step: per-wave LDS ping (u32-typed, TBAA-safe, no fence) reshapes
// p into the MFMA B-operand (P^T); A-operand = V^T frags from VT.
// pvbuf and the cross-wave out-reduce buffer alias one LDS region (35.3 KB total).
__launch_bounds__(512, 4)
__global__ void k_attn_pv(const unsigned short* __restrict__ qh, const unsigned short* __restrict__ ql,
                          const unsigned short* __restrict__ kh, const unsigned short* __restrict__ kl,
                          const unsigned short* __restrict__ VT, const float* __restrict__ posb,
                          float* __restrict__ attn, unsigned short* __restrict__ oc) {
  // XCD swizzle: 128 consecutive logical blocks share one (b,h) K/V slice.
  const int bid = (int)((blockIdx.x & 7) * 512 + (blockIdx.x >> 3));
  const int qt = bid & 127;
  const int h = (bid >> 7) & 15;
  const int b = bid >> 11;
  const int t = threadIdx.x;
  const int wid = t >> 6, l = t & 63, g = l >> 4, c = l & 15;
  const int jb0 = wid * 256;

  // union region: loop phase = per-wave p-ping (8 x 640 u32 = 20.5 KB);
  // epilogue = padded partial-out [8][16][68] f32 (34.8 KB). 8704 u32 total.
  __shared__ unsigned smem[8704];
  __shared__ float red[8][16];
  unsigned* myping = &smem[wid * 640];

  const size_t qoff = ((size_t)(qt * 16 + c) * 2 + b) * 1024 + h * 64 + g * 8;
  const bf16x8 qfh0 = *(const bf16x8*)(qh + qoff);
  const bf16x8 qfh1 = *(const bf16x8*)(qh + qoff + 32);
  const bf16x8 qfl0 = *(const bf16x8*)(ql + qoff);
  const bf16x8 qfl1 = *(const bf16x8*)(ql + qoff + 32);

  const float* pb = posb + (size_t)b * S_ * S_ + (size_t)(qt * 16 + c) * S_ + jb0;
  const unsigned short* Vbase = VT + ((size_t)b * 1024 + h * 64) * 2048;

  unsigned psc0[16], psc1[16];
  float lsum = 0.f;
  f32x4 oacc[4] = {};

  #pragma unroll
  for (int st = 0; st < 8; ++st) {
    #pragma unroll
    for (int th = 0; th < 2; ++th) {
      const int tt = st * 2 + th;
      const size_t koff = ((size_t)(jb0 + tt * 16 + c) * 2 + b) * 1024 + h * 64 + g * 8;
      bf16x8 kfh0 = *(const bf16x8*)(kh + koff);
      bf16x8 kfh1 = *(const bf16x8*)(kh + koff + 32);
      bf16x8 kfl0 = *(const bf16x8*)(kl + koff);
      bf16x8 kfl1 = *(const bf16x8*)(kl + koff + 32);
      f32x4 bias4 = *(const f32x4*)(pb + tt * 16 + 4 * g);
      f32x4 acc = {};
      acc = __builtin_amdgcn_mfma_f32_16x16x32_bf16(kfh0, qfh0, acc, 0, 0, 0);
      acc = __builtin_amdgcn_mfma_f32_16x16x32_bf16(kfh1, qfh1, acc, 0, 0, 0);
      acc = __builtin_amdgcn_mfma_f32_16x16x32_bf16(kfl0, qfh0, acc, 0, 0, 0);
      acc = __builtin_amdgcn_mfma_f32_16x16x32_bf16(kfl1, qfh1, acc, 0, 0, 0);
      acc = __builtin_amdgcn_mfma_f32_16x16x32_bf16(kfh0, qfl0, acc, 0, 0, 0);
      acc = __builtin_amdgcn_mfma_f32_16x16x32_bf16(kfh1, qfl1, acc, 0, 0, 0);
      float p0 = __expf(acc[0] + bias4[0]);
      float p1 = __expf(acc[1] + bias4[1]);
      float p2 = __expf(acc[2] + bias4[2]);
      float p3 = __expf(acc[3] + bias4[3]);
      lsum += (p0 + p1) + (p2 + p3);
      psc0[tt] = pk_bf16(p0, p1);
      psc1[tt] = pk_bf16(p2, p3);
    }
    // ---- PV for this 32-k step ----
    // row layout per q=c: u32 j holds k-pair (2j, 2j+1), j = th*8 + 2g (+1)
    unsigned* pg = myping + (st & 1) * 320;
    pg[c * 20 + 2 * g]         = psc0[st * 2];
    pg[c * 20 + 2 * g + 1]     = psc1[st * 2];
    pg[c * 20 + 8 + 2 * g]     = psc0[st * 2 + 1];
    pg[c * 20 + 8 + 2 * g + 1] = psc1[st * 2 + 1];
    // read B-frag (P^T): k = 8g..8g+7, q = c (u32-typed: same TBAA class as writes,
    // so ordering is preserved without a fence; DS ops are wave-ordered in HW)
    u32x4 braw = *(u32x4*)&pg[c * 20 + 4 * g];
    bf16x8 bfrag = __builtin_bit_cast(bf16x8, braw);
    #pragma unroll
    for (int dtile = 0; dtile < 4; ++dtile) {
      bf16x8 vfrag = *(const bf16x8*)(Vbase + (size_t)(dtile * 16 + c) * 2048 + jb0 + st * 32 + g * 8);
      oacc[dtile] = __builtin_amdgcn_mfma_f32_16x16x32_bf16(vfrag, bfrag, oacc[dtile], 0, 0, 0);
    }
  }

  // softmax denominator across g within wave, then across 8 waves
  lsum += __shfl_xor(lsum, 16, 64);
  lsum += __shfl_xor(lsum, 32, 64);
  if (l < 16) red[wid][l] = lsum;
  __syncthreads();   // also: all pvbuf use done -> smem region reusable as ored
  const float inv = 1.0f / (((red[0][c] + red[1][c]) + (red[2][c] + red[3][c])) +
                            ((red[4][c] + red[5][c]) + (red[6][c] + red[7][c])));

  // scaled partial out -> LDS (padded stride 68 to avoid 16-way bank conflicts)
  float* ored = (float*)smem;   // [8][16][68]
  #pragma unroll
  for (int dtile = 0; dtile < 4; ++dtile) {
    f32x4 o = oacc[dtile];
    o[0] *= inv; o[1] *= inv; o[2] *= inv; o[3] *= inv;
    *(f32x4*)&ored[(wid * 16 + c) * 68 + dtile * 16 + 4 * g] = o;
  }
  __syncthreads();

  // cross-wave reduce (1024 outputs, 2 per thread) -> oc (bf16)
  {
    const int q = t >> 5;
    const int d = (t & 31) * 2;
    float s0 = 0.f, s1 = 0.f;
    #pragma unroll
    for (int w = 0; w < 8; ++w) {
      s0 += ored[((w * 16) + q) * 68 + d];
      s1 += ored[((w * 16) + q) * 68 + d + 1];
    }
    unsigned pk = pk_bf16(s0, s1);
    *(unsigned*)&oc[((size_t)(qt * 16 + q) * 2 + b) * 1024 + h * 64 + d] = pk;
  }

  // attn write (normalized), nontemporal 16B per lane per tile
  float* arow = attn + ((size_t)(b * 16 + h) * S_ + qt * 16 + c) * S_ + jb0;
  #pragma unroll
  for (int tt = 0; tt < 16; ++tt) {
    f32x4 o;
    o[0] = __uint_as_float(psc0[tt] << 16) * inv;
    o[1] = __uint_as_float(psc0[tt] & 0xFFFF0000u) * inv;
    o[2] = __uint_as_float(psc1[tt] << 16) * inv;
    o[3] = __uint_as_float(psc1[tt] & 0xFFFF0000u) * inv;
    __builtin_nontemporal_store(o, (f32x4*)(arow + tt * 16 + 4 * g));
  }
}

// ---------------- out projection ----------------
__launch_bounds__(256, 2)
__global__ void k_outproj(const unsigned short* __restrict__ oc, const unsigned short* __restrict__ ow,
                          const float* __restrict__ ob, float* __restrict__ out) {
  __shared__ unsigned short sA[128][40], sB[128][40];
  const int t = threadIdx.x;
  const int wid = t >> 6, l = t & 63, g = l >> 4, c = l & 15;
  const int wr = wid >> 1, wc = wid & 1;
  const int mb = blockIdx.x * 128, nb = blockIdx.y * 128;
  const int sr = t >> 1, sc = (t & 1) * 16;

  f32x4 acc[4][4] = {};
  for (int k0 = 0; k0 < 1024; k0 += 32) {
    __syncthreads();
    {
      const unsigned short* pa = oc + (size_t)(mb + sr) * 1024 + k0 + sc;
      const unsigned short* pbp = ow + (size_t)(nb + sr) * 1024 + k0 + sc;
      *(bf16x8*)&sA[sr][sc]     = *(const bf16x8*)pa;
      *(bf16x8*)&sA[sr][sc + 8] = *(const bf16x8*)(pa + 8);
      *(bf16x8*)&sB[sr][sc]     = *(const bf16x8*)pbp;
      *(bf16x8*)&sB[sr][sc + 8] = *(const bf16x8*)(pbp + 8);
    }
    __syncthreads();
    bf16x8 af[4], bfr[4];
    #pragma unroll
    for (int i = 0; i < 4; ++i) {
      af[i]  = *(const bf16x8*)&sA[wr * 64 + i * 16 + c][g * 8];
      bfr[i] = *(const bf16x8*)&sB[wc * 64 + i * 16 + c][g * 8];
    }
    #pragma unroll
    for (int i = 0; i < 4; ++i)
      #pragma unroll
      for (int j = 0; j < 4; ++j)
        acc[i][j] = __builtin_amdgcn_mfma_f32_16x16x32_bf16(af[i], bfr[j], acc[i][j], 0, 0, 0);
  }
  #pragma unroll
  for (int i = 0; i < 4; ++i)
    #pragma unroll
    for (int j = 0; j < 4; ++j)
      #pragma unroll
      for (int rr = 0; rr < 4; ++rr) {
        int m = mb + wr * 64 + i * 16 + 4 * g + rr;
        int n = nb + wc * 64 + j * 16 + c;
        out[(size_t)m * 1024 + n] = acc[i][j][rr] + ob[n];
      }
}

extern "C" void kernel_launch(void* const* d_in, const int* in_sizes, int n_in,
                              void* d_out, int out_size, void* d_ws, size_t ws_size,
                              hipStream_t stream) {
  (void)in_sizes; (void)n_in; (void)out_size; (void)ws_size;
  const float* query = (const float*)d_in[0];
  const float* keyi  = (const float*)d_in[1];
  const float* value = (const float*)d_in[2];
  const float* posb  = (const float*)d_in[3];
  const float* ipw   = (const float*)d_in[4];
  const float* ipb   = (const float*)d_in[5];
  const float* outw  = (const float*)d_in[6];
  const float* outb  = (const float*)d_in[7];
  float* out = (float*)d_out;
  float* attn = out + (size_t)S_ * B_ * E_;

  char* ws = (char*)d_ws;
  size_t off = 0;
  auto alloc = [&](size_t bytes) -> void* {
    void* p = ws + off;
    off += (bytes + 255) & ~(size_t)255;
    return p;
  };
  const size_t NTOK = (size_t)S_ * B_;  // 4096
  unsigned short* qxh = (unsigned short*)alloc(NTOK * 1024 * 2);
  unsigned short* qxl = (unsigned short*)alloc(NTOK * 1024 * 2);
  unsigned short* kxh = (unsigned short*)alloc(NTOK * 1024 * 2);
  unsigned short* kxl = (unsigned short*)alloc(NTOK * 1024 * 2);
  unsigned short* vx  = (unsigned short*)alloc(NTOK * 1024 * 2);
  unsigned short* wh  = (unsigned short*)alloc((size_t)2048 * 1024 * 2);
  unsigned short* wl  = (unsigned short*)alloc((size_t)2048 * 1024 * 2);
  unsigned short* wv  = (unsigned short*)alloc((size_t)1024 * 1024 * 2);
  unsigned short* ow  = (unsigned short*)alloc((size_t)1024 * 1024 * 2);
  unsigned short* qh  = (unsigned short*)alloc(NTOK * 1024 * 2);
  unsigned short* ql  = (unsigned short*)alloc(NTOK * 1024 * 2);
  unsigned short* kh  = (unsigned short*)alloc(NTOK * 1024 * 2);
  unsigned short* kl  = (unsigned short*)alloc(NTOK * 1024 * 2);
  unsigned short* VT  = (unsigned short*)alloc((size_t)2 * 1024 * 2048 * 2);
  unsigned short* oc  = (unsigned short*)alloc(NTOK * 1024 * 2);

  const int n1_4 = (int)(NTOK * 1024 / 4);
  k_split2<<<2048, 256, 0, stream>>>(query, qxh, qxl, n1_4);
  k_split2<<<2048, 256, 0, stream>>>(keyi, kxh, kxl, n1_4);
  k_cvt<<<2048, 256, 0, stream>>>(value, vx, n1_4);
  k_split2<<<1024, 256, 0, stream>>>(ipw, wh, wl, 2048 * 1024 / 4);
  k_cvt<<<512, 256, 0, stream>>>(ipw + 2048 * 1024, wv, 1024 * 1024 / 4);
  k_cvt<<<512, 256, 0, stream>>>(outw, ow, 1024 * 1024 / 4);

  k_proj_qk<<<dim3(32, 8, 2), 256, 0, stream>>>(qxh, qxl, kxh, kxl, wh, wl, ipb, qh, ql, kh, kl);
  k_proj_v<<<dim3(8, 32), 256, 0, stream>>>(wv, vx, ipb, VT);
  k_attn_pv<<<4096, 512, 0, stream>>>(qh, ql, kh, kl, VT, posb, attn, oc);
  k_outproj<<<dim3(32, 8), 256, 0, stream>>>(oc, ow, outb, out);
}

// Round 6
// 493.179 us; speedup vs baseline: 1.5839x; 1.2583x over previous
//
#include <hip/hip_runtime.h>

#define S_ 2048
#define B_ 2
#define E_ 1024
#define H_ 16

typedef __bf16 bf16x8 __attribute__((ext_vector_type(8)));
typedef float f32x4 __attribute__((ext_vector_type(4)));
typedef unsigned short us4_t __attribute__((ext_vector_type(4)));
typedef unsigned u32x4 __attribute__((ext_vector_type(4)));
typedef unsigned u32x2 __attribute__((ext_vector_type(2)));

static __device__ __forceinline__ unsigned short f2bf(float x) {
  union { float f; unsigned u; } v; v.f = x;
  unsigned r = v.u + 0x7fffu + ((v.u >> 16) & 1u);
  return (unsigned short)(r >> 16);
}
static __device__ __forceinline__ float bf2f(unsigned short h) {
  union { unsigned u; float f; } v; v.u = ((unsigned)h) << 16;
  return v.f;
}
static __device__ __forceinline__ unsigned pk_bf16(float a, float b) {
  unsigned r;
  asm("v_cvt_pk_bf16_f32 %0, %1, %2" : "=v"(r) : "v"(a), "v"(b));
  return r;
}

// ---------------- elementwise split / convert (vectorized) ----------------
__global__ void k_split2(const float* __restrict__ src, unsigned short* __restrict__ hi,
                         unsigned short* __restrict__ lo, int n4) {
  int i = blockIdx.x * blockDim.x + threadIdx.x;
  int st = gridDim.x * blockDim.x;
  for (; i < n4; i += st) {
    f32x4 x = ((const f32x4*)src)[i];
    us4_t h, lw;
    #pragma unroll
    for (int j = 0; j < 4; ++j) {
      unsigned short hh = f2bf(x[j]);
      h[j] = hh;
      lw[j] = f2bf(x[j] - bf2f(hh));
    }
    ((us4_t*)hi)[i] = h;
    ((us4_t*)lo)[i] = lw;
  }
}

__global__ void k_cvt(const float* __restrict__ src, unsigned short* __restrict__ dst, int n4) {
  int i = blockIdx.x * blockDim.x + threadIdx.x;
  int st = gridDim.x * blockDim.x;
  for (; i < n4; i += st) {
    f32x4 x = ((const f32x4*)src)[i];
    us4_t h;
    #pragma unroll
    for (int j = 0; j < 4; ++j) h[j] = f2bf(x[j]);
    ((us4_t*)dst)[i] = h;
  }
}

// ---------------- q/k projection: 3-term split GEMM ----------------
__launch_bounds__(256, 2)
__global__ void k_proj_qk(const unsigned short* __restrict__ qxh, const unsigned short* __restrict__ qxl,
                          const unsigned short* __restrict__ kxh, const unsigned short* __restrict__ kxl,
                          const unsigned short* __restrict__ wh, const unsigned short* __restrict__ wl,
                          const float* __restrict__ bias,
                          unsigned short* __restrict__ qh, unsigned short* __restrict__ ql,
                          unsigned short* __restrict__ kh, unsigned short* __restrict__ kl) {
  const int z = blockIdx.z;
  const unsigned short* Ah = z ? kxh : qxh;
  const unsigned short* Al = z ? kxl : qxl;
  const unsigned short* Bh = wh + (size_t)z * (1024 * 1024);
  const unsigned short* Bl = wl + (size_t)z * (1024 * 1024);
  unsigned short* Ch = z ? kh : qh;
  unsigned short* Cl = z ? kl : ql;
  const float* bia = bias + z * 1024;
  const float scale = z ? 1.0f : 0.125f;

  __shared__ unsigned short sAh[128][40], sAl[128][40], sBh[128][40], sBl[128][40];

  const int t = threadIdx.x;
  const int wid = t >> 6, l = t & 63, g = l >> 4, c = l & 15;
  const int wr = wid >> 1, wc = wid & 1;
  const int mb = blockIdx.x * 128, nb = blockIdx.y * 128;
  const int sr = t >> 1, sc = (t & 1) * 16;

  f32x4 acc[4][4] = {};

  for (int k0 = 0; k0 < 1024; k0 += 32) {
    __syncthreads();
    {
      const unsigned short* pah = Ah + (size_t)(mb + sr) * 1024 + k0 + sc;
      const unsigned short* pal = Al + (size_t)(mb + sr) * 1024 + k0 + sc;
      const unsigned short* pbh = Bh + (size_t)(nb + sr) * 1024 + k0 + sc;
      const unsigned short* pbl = Bl + (size_t)(nb + sr) * 1024 + k0 + sc;
      *(bf16x8*)&sAh[sr][sc]     = *(const bf16x8*)pah;
      *(bf16x8*)&sAh[sr][sc + 8] = *(const bf16x8*)(pah + 8);
      *(bf16x8*)&sAl[sr][sc]     = *(const bf16x8*)pal;
      *(bf16x8*)&sAl[sr][sc + 8] = *(const bf16x8*)(pal + 8);
      *(bf16x8*)&sBh[sr][sc]     = *(const bf16x8*)pbh;
      *(bf16x8*)&sBh[sr][sc + 8] = *(const bf16x8*)(pbh + 8);
      *(bf16x8*)&sBl[sr][sc]     = *(const bf16x8*)pbl;
      *(bf16x8*)&sBl[sr][sc + 8] = *(const bf16x8*)(pbl + 8);
    }
    __syncthreads();
    bf16x8 afh[4], afl[4], bfh[4], bfl[4];
    #pragma unroll
    for (int i = 0; i < 4; ++i) {
      afh[i] = *(const bf16x8*)&sAh[wr * 64 + i * 16 + c][g * 8];
      afl[i] = *(const bf16x8*)&sAl[wr * 64 + i * 16 + c][g * 8];
      bfh[i] = *(const bf16x8*)&sBh[wc * 64 + i * 16 + c][g * 8];
      bfl[i] = *(const bf16x8*)&sBl[wc * 64 + i * 16 + c][g * 8];
    }
    #pragma unroll
    for (int i = 0; i < 4; ++i)
      #pragma unroll
      for (int j = 0; j < 4; ++j) {
        acc[i][j] = __builtin_amdgcn_mfma_f32_16x16x32_bf16(afh[i], bfh[j], acc[i][j], 0, 0, 0);
        acc[i][j] = __builtin_amdgcn_mfma_f32_16x16x32_bf16(afh[i], bfl[j], acc[i][j], 0, 0, 0);
        acc[i][j] = __builtin_amdgcn_mfma_f32_16x16x32_bf16(afl[i], bfh[j], acc[i][j], 0, 0, 0);
      }
  }
  #pragma unroll
  for (int i = 0; i < 4; ++i)
    #pragma unroll
    for (int j = 0; j < 4; ++j)
      #pragma unroll
      for (int rr = 0; rr < 4; ++rr) {
        int m = mb + wr * 64 + i * 16 + 4 * g + rr;
        int n = nb + wc * 64 + j * 16 + c;
        float v = (acc[i][j][rr] + bia[n]) * scale;
        unsigned short hh = f2bf(v);
        size_t idx = (size_t)m * 1024 + n;
        Ch[idx] = hh;
        Cl[idx] = f2bf(v - bf2f(hh));
      }
}

// ---------------- v projection, writes V^T layout: VT[b][e'][j] ----------------
__launch_bounds__(256, 2)
__global__ void k_proj_v(const unsigned short* __restrict__ wv, const unsigned short* __restrict__ vx,
                         const float* __restrict__ bias, unsigned short* __restrict__ VT) {
  __shared__ unsigned short sA[128][40], sB[128][40];
  const int t = threadIdx.x;
  const int wid = t >> 6, l = t & 63, g = l >> 4, c = l & 15;
  const int wr = wid >> 1, wc = wid & 1;
  const int mb = blockIdx.x * 128;   // e' base
  const int nb = blockIdx.y * 128;   // n = b*2048 + j
  const int bb = nb >> 11;
  const int jb = nb & 2047;
  const int sr = t >> 1, sc = (t & 1) * 16;

  f32x4 acc[4][4] = {};
  for (int k0 = 0; k0 < 1024; k0 += 32) {
    __syncthreads();
    {
      const unsigned short* pa = wv + (size_t)(mb + sr) * 1024 + k0 + sc;
      const unsigned short* pbp = vx + ((size_t)(jb + sr) * 2 + bb) * 1024 + k0 + sc;
      *(bf16x8*)&sA[sr][sc]     = *(const bf16x8*)pa;
      *(bf16x8*)&sA[sr][sc + 8] = *(const bf16x8*)(pa + 8);
      *(bf16x8*)&sB[sr][sc]     = *(const bf16x8*)pbp;
      *(bf16x8*)&sB[sr][sc + 8] = *(const bf16x8*)(pbp + 8);
    }
    __syncthreads();
    bf16x8 af[4], bfr[4];
    #pragma unroll
    for (int i = 0; i < 4; ++i) {
      af[i]  = *(const bf16x8*)&sA[wr * 64 + i * 16 + c][g * 8];
      bfr[i] = *(const bf16x8*)&sB[wc * 64 + i * 16 + c][g * 8];
    }
    #pragma unroll
    for (int i = 0; i < 4; ++i)
      #pragma unroll
      for (int j = 0; j < 4; ++j)
        acc[i][j] = __builtin_amdgcn_mfma_f32_16x16x32_bf16(af[i], bfr[j], acc[i][j], 0, 0, 0);
  }
  #pragma unroll
  for (int i = 0; i < 4; ++i)
    #pragma unroll
    for (int j = 0; j < 4; ++j)
      #pragma unroll
      for (int rr = 0; rr < 4; ++rr) {
        int m = mb + wr * 64 + i * 16 + 4 * g + rr;
        int jj = jb + wc * 64 + j * 16 + c;
        float v = acc[i][j][rr] + bias[2048 + m];
        VT[(size_t)bb * (1024 * 2048) + (size_t)m * 2048 + jj] = f2bf(v);
      }
}

// ---------------- fused attention, staged-pipeline version ----------------
// Block = (b,h,qt): 16 q-rows, 256 threads = 4 waves. Wave ct owns col-tile
// ct*16 within each staged KVBLK=64. K-hi/K-lo/V^T staged in LDS (dbuf),
// pre-swizzled global source + linear LDS write + swizzled read (T2/rule 21).
// Swapped QK: acc[rr]@(g,c) = s[k=4g+rr][q=c]. Ping shared per ct-pair gives
// PV a K=32 B-operand; wave does dtiles for its d-half. psc keeps p (bf16
// packed) for the attn write; no-max softmax (|s|<~20).
__launch_bounds__(256, 3)
__global__ void k_attn_pv(const unsigned short* __restrict__ qh, const unsigned short* __restrict__ ql,
                          const unsigned short* __restrict__ kh, const unsigned short* __restrict__ kl,
                          const unsigned short* __restrict__ VT, const float* __restrict__ posb,
                          float* __restrict__ attn, unsigned short* __restrict__ oc) {
  // XCD chunking, h-major: each XCD gets 2 heads -> K/V working set ~3MB fits L2.
  const int swz = (int)((blockIdx.x & 7) * 512 + (blockIdx.x >> 3));
  const int h = swz >> 8;
  const int b = (swz >> 7) & 1;
  const int qt = swz & 127;

  const int t = threadIdx.x;
  const int wid = t >> 6, l = t & 63, g = l >> 4, c = l & 15;
  const int ct = wid;               // col-tile 0..3
  const int ctpair = ct >> 1, half = ct & 1;

  __shared__ unsigned lds_kh[2][2048];   // 64 rows x 32 u32 (128B rows)
  __shared__ unsigned lds_kl[2][2048];
  __shared__ unsigned lds_vt[2][2048];
  __shared__ unsigned lds_ping[2][320];  // per ct-pair: 16q x 20 u32
  __shared__ float lds_red[4][16];

  // ---- Q fragments (one q-tile) ----
  const size_t qoff = ((size_t)(qt * 16 + c) * 2 + b) * 1024 + h * 64 + g * 8;
  const bf16x8 qfh0 = *(const bf16x8*)(qh + qoff);
  const bf16x8 qfh1 = *(const bf16x8*)(qh + qoff + 32);
  const bf16x8 qfl0 = *(const bf16x8*)(ql + qoff);
  const bf16x8 qfl1 = *(const bf16x8*)(ql + qoff + 32);

  const unsigned short* khb = kh + (size_t)b * 1024 + h * 64;
  const unsigned short* klb = kl + (size_t)b * 1024 + h * 64;
  const unsigned short* vtb = VT + ((size_t)b * 1024 + h * 64) * 2048;
  const float* pbRow = posb + (size_t)b * S_ * S_ + (size_t)(qt * 16 + c) * S_ + ct * 16;

  // staging map: thread t -> row=t>>2 (64 rows), phys slots {2(t&3), 2(t&3)+1};
  // global slot = phys ^ (row&7)  (pre-swizzled source, linear LDS dest)
  const int srow = t >> 2;
  const int sw = srow & 7;
  const int s0 = ((t & 3) * 2) ^ sw;
  const int s1 = ((t & 3) * 2 + 1) ^ sw;

  // swizzled-read helper: logical 16B slot `slot` of row `row`
  #define LDSRD(buf, row, slot) \
    __builtin_bit_cast(bf16x8, *(const u32x4*)&(buf)[(row) * 32 + (((slot) ^ ((row) & 7)) * 4)])

  unsigned psc0[32], psc1[32];
  float lsum = 0.f;
  f32x4 oacc[2] = {};

  // ---- prologue: stage 0 into buf 0 ----
  {
    const size_t r0 = (size_t)srow * 2048;
    u32x4 a0 = *(const u32x4*)(khb + r0 + s0 * 8);
    u32x4 a1 = *(const u32x4*)(khb + r0 + s1 * 8);
    u32x4 b0 = *(const u32x4*)(klb + r0 + s0 * 8);
    u32x4 b1 = *(const u32x4*)(klb + r0 + s1 * 8);
    u32x4 v0 = *(const u32x4*)(vtb + r0 + s0 * 8);
    u32x4 v1 = *(const u32x4*)(vtb + r0 + s1 * 8);
    *(u32x4*)&lds_kh[0][t * 8] = a0;  *(u32x4*)&lds_kh[0][t * 8 + 4] = a1;
    *(u32x4*)&lds_kl[0][t * 8] = b0;  *(u32x4*)&lds_kl[0][t * 8 + 4] = b1;
    *(u32x4*)&lds_vt[0][t * 8] = v0;  *(u32x4*)&lds_vt[0][t * 8 + 4] = v1;
  }
  __syncthreads();

  #pragma unroll
  for (int st = 0; st < 32; ++st) {
    const int buf = st & 1;
    // ---- prefetch stage st+1 (issue loads early) ----
    u32x4 a0, a1, b0, b1, v0, v1;
    if (st < 31) {
      const int c1 = (st + 1) * 64;
      const size_t rk = (size_t)(c1 + srow) * 2048;
      const size_t rv = (size_t)srow * 2048 + c1;
      a0 = *(const u32x4*)(khb + rk + s0 * 8);
      a1 = *(const u32x4*)(khb + rk + s1 * 8);
      b0 = *(const u32x4*)(klb + rk + s0 * 8);
      b1 = *(const u32x4*)(klb + rk + s1 * 8);
      v0 = *(const u32x4*)(vtb + rv + s0 * 8);
      v1 = *(const u32x4*)(vtb + rv + s1 * 8);
    }
    // ---- QK for this wave's 16-col tile ----
    {
      const int row = ct * 16 + c;
      bf16x8 kfh0 = LDSRD(lds_kh[buf], row, g);
      bf16x8 kfh1 = LDSRD(lds_kh[buf], row, 4 + g);
      bf16x8 kfl0 = LDSRD(lds_kl[buf], row, g);
      bf16x8 kfl1 = LDSRD(lds_kl[buf], row, 4 + g);
      f32x4 bias4 = *(const f32x4*)(pbRow + st * 64 + 4 * g);
      f32x4 acc = {};
      acc = __builtin_amdgcn_mfma_f32_16x16x32_bf16(kfh0, qfh0, acc, 0, 0, 0);
      acc = __builtin_amdgcn_mfma_f32_16x16x32_bf16(kfh1, qfh1, acc, 0, 0, 0);
      acc = __builtin_amdgcn_mfma_f32_16x16x32_bf16(kfl0, qfh0, acc, 0, 0, 0);
      acc = __builtin_amdgcn_mfma_f32_16x16x32_bf16(kfl1, qfh1, acc, 0, 0, 0);
      acc = __builtin_amdgcn_mfma_f32_16x16x32_bf16(kfh0, qfl0, acc, 0, 0, 0);
      acc = __builtin_amdgcn_mfma_f32_16x16x32_bf16(kfh1, qfl1, acc, 0, 0, 0);
      float p0 = __expf(acc[0] + bias4[0]);
      float p1 = __expf(acc[1] + bias4[1]);
      float p2 = __expf(acc[2] + bias4[2]);
      float p3 = __expf(acc[3] + bias4[3]);
      lsum += (p0 + p1) + (p2 + p3);
      psc0[st] = pk_bf16(p0, p1);
      psc1[st] = pk_bf16(p2, p3);
      // ping: pair-shared, u32 j = k-pair index (half*8 + 2g [+1])
      lds_ping[ctpair][c * 20 + half * 8 + 2 * g]     = psc0[st];
      lds_ping[ctpair][c * 20 + half * 8 + 2 * g + 1] = psc1[st];
    }
    __syncthreads();   // ping complete (pair waves), staging buf still intact
    // ---- PV: K=32 over the pair's cols; this wave does its d-half ----
    {
      u32x4 braw = *(const u32x4*)&lds_ping[ctpair][c * 20 + 4 * g];
      bf16x8 bfrag = __builtin_bit_cast(bf16x8, braw);
      #pragma unroll
      for (int dt = 0; dt < 2; ++dt) {
        const int row = half * 32 + dt * 16 + c;
        bf16x8 vfrag = LDSRD(lds_vt[buf], row, ctpair * 4 + g);
        oacc[dt] = __builtin_amdgcn_mfma_f32_16x16x32_bf16(vfrag, bfrag, oacc[dt], 0, 0, 0);
      }
    }
    // ---- write staged regs into other buffer ----
    if (st < 31) {
      const int nb = buf ^ 1;
      *(u32x4*)&lds_kh[nb][t * 8] = a0;  *(u32x4*)&lds_kh[nb][t * 8 + 4] = a1;
      *(u32x4*)&lds_kl[nb][t * 8] = b0;  *(u32x4*)&lds_kl[nb][t * 8 + 4] = b1;
      *(u32x4*)&lds_vt[nb][t * 8] = v0;  *(u32x4*)&lds_vt[nb][t * 8 + 4] = v1;
    }
    __syncthreads();   // staging done; ping consumable for rewrite next stage
  }

  // ---- softmax denominator ----
  lsum += __shfl_xor(lsum, 16, 64);
  lsum += __shfl_xor(lsum, 32, 64);
  if (l < 16) lds_red[ct][c] = lsum;
  __syncthreads();
  const float inv = 1.0f / ((lds_red[0][c] + lds_red[1][c]) + (lds_red[2][c] + lds_red[3][c]));

  // ---- cross-wave out reduce (ored aliases staging LDS; barrier-guarded) ----
  float* ored = (float*)&lds_kh[0][0];   // [2 pairs][16 q][68]
  #pragma unroll
  for (int dt = 0; dt < 2; ++dt) {
    f32x4 o = oacc[dt];
    o[0] *= inv; o[1] *= inv; o[2] *= inv; o[3] *= inv;
    *(f32x4*)&ored[(ctpair * 16 + c) * 68 + half * 32 + dt * 16 + 4 * g] = o;
  }
  __syncthreads();
  {
    const int q = t >> 4;
    const int d0 = (t & 15) * 4;
    f32x4 sA = *(const f32x4*)&ored[(0 * 16 + q) * 68 + d0];
    f32x4 sB = *(const f32x4*)&ored[(1 * 16 + q) * 68 + d0];
    f32x4 s;
    s[0] = sA[0] + sB[0]; s[1] = sA[1] + sB[1];
    s[2] = sA[2] + sB[2]; s[3] = sA[3] + sB[3];
    u32x2 pk;
    pk[0] = pk_bf16(s[0], s[1]);
    pk[1] = pk_bf16(s[2], s[3]);
    *(u32x2*)&oc[((size_t)(qt * 16 + q) * 2 + b) * 1024 + h * 64 + d0] = pk;
  }

  // ---- attn write (normalized) ----
  float* arow = attn + ((size_t)(b * 16 + h) * S_ + qt * 16 + c) * S_ + ct * 16;
  #pragma unroll
  for (int st = 0; st < 32; ++st) {
    f32x4 o;
    o[0] = __uint_as_float(psc0[st] << 16) * inv;
    o[1] = __uint_as_float(psc0[st] & 0xFFFF0000u) * inv;
    o[2] = __uint_as_float(psc1[st] << 16) * inv;
    o[3] = __uint_as_float(psc1[st] & 0xFFFF0000u) * inv;
    *(f32x4*)(arow + (size_t)st * 64 + 4 * g) = o;
  }
  #undef LDSRD
}

// ---------------- out projection ----------------
__launch_bounds__(256, 2)
__global__ void k_outproj(const unsigned short* __restrict__ oc, const unsigned short* __restrict__ ow,
                          const float* __restrict__ ob, float* __restrict__ out) {
  __shared__ unsigned short sA[128][40], sB[128][40];
  const int t = threadIdx.x;
  const int wid = t >> 6, l = t & 63, g = l >> 4, c = l & 15;
  const int wr = wid >> 1, wc = wid & 1;
  const int mb = blockIdx.x * 128, nb = blockIdx.y * 128;
  const int sr = t >> 1, sc = (t & 1) * 16;

  f32x4 acc[4][4] = {};
  for (int k0 = 0; k0 < 1024; k0 += 32) {
    __syncthreads();
    {
      const unsigned short* pa = oc + (size_t)(mb + sr) * 1024 + k0 + sc;
      const unsigned short* pbp = ow + (size_t)(nb + sr) * 1024 + k0 + sc;
      *(bf16x8*)&sA[sr][sc]     = *(const bf16x8*)pa;
      *(bf16x8*)&sA[sr][sc + 8] = *(const bf16x8*)(pa + 8);
      *(bf16x8*)&sB[sr][sc]     = *(const bf16x8*)pbp;
      *(bf16x8*)&sB[sr][sc + 8] = *(const bf16x8*)(pbp + 8);
    }
    __syncthreads();
    bf16x8 af[4], bfr[4];
    #pragma unroll
    for (int i = 0; i < 4; ++i) {
      af[i]  = *(const bf16x8*)&sA[wr * 64 + i * 16 + c][g * 8];
      bfr[i] = *(const bf16x8*)&sB[wc * 64 + i * 16 + c][g * 8];
    }
    #pragma unroll
    for (int i = 0; i < 4; ++i)
      #pragma unroll
      for (int j = 0; j < 4; ++j)
        acc[i][j] = __builtin_amdgcn_mfma_f32_16x16x32_bf16(af[i], bfr[j], acc[i][j], 0, 0, 0);
  }
  #pragma unroll
  for (int i = 0; i < 4; ++i)
    #pragma unroll
    for (int j = 0; j < 4; ++j)
      #pragma unroll
      for (int rr = 0; rr < 4; ++rr) {
        int m = mb + wr * 64 + i * 16 + 4 * g + rr;
        int n = nb + wc * 64 + j * 16 + c;
        out[(size_t)m * 1024 + n] = acc[i][j][rr] + ob[n];
      }
}

extern "C" void kernel_launch(void* const* d_in, const int* in_sizes, int n_in,
                              void* d_out, int out_size, void* d_ws, size_t ws_size,
                              hipStream_t stream) {
  (void)in_sizes; (void)n_in; (void)out_size; (void)ws_size;
  const float* query = (const float*)d_in[0];
  const float* keyi  = (const float*)d_in[1];
  const float* value = (const float*)d_in[2];
  const float* posb  = (const float*)d_in[3];
  const float* ipw   = (const float*)d_in[4];
  const float* ipb   = (const float*)d_in[5];
  const float* outw  = (const float*)d_in[6];
  const float* outb  = (const float*)d_in[7];
  float* out = (float*)d_out;
  float* attn = out + (size_t)S_ * B_ * E_;

  char* ws = (char*)d_ws;
  size_t off = 0;
  auto alloc = [&](size_t bytes) -> void* {
    void* p = ws + off;
    off += (bytes + 255) & ~(size_t)255;
    return p;
  };
  const size_t NTOK = (size_t)S_ * B_;  // 4096
  unsigned short* qxh = (unsigned short*)alloc(NTOK * 1024 * 2);
  unsigned short* qxl = (unsigned short*)alloc(NTOK * 1024 * 2);
  unsigned short* kxh = (unsigned short*)alloc(NTOK * 1024 * 2);
  unsigned short* kxl = (unsigned short*)alloc(NTOK * 1024 * 2);
  unsigned short* vx  = (unsigned short*)alloc(NTOK * 1024 * 2);
  unsigned short* wh  = (unsigned short*)alloc((size_t)2048 * 1024 * 2);
  unsigned short* wl  = (unsigned short*)alloc((size_t)2048 * 1024 * 2);
  unsigned short* wv  = (unsigned short*)alloc((size_t)1024 * 1024 * 2);
  unsigned short* ow  = (unsigned short*)alloc((size_t)1024 * 1024 * 2);
  unsigned short* qh  = (unsigned short*)alloc(NTOK * 1024 * 2);
  unsigned short* ql  = (unsigned short*)alloc(NTOK * 1024 * 2);
  unsigned short* kh  = (unsigned short*)alloc(NTOK * 1024 * 2);
  unsigned short* kl  = (unsigned short*)alloc(NTOK * 1024 * 2);
  unsigned short* VT  = (unsigned short*)alloc((size_t)2 * 1024 * 2048 * 2);
  unsigned short* oc  = (unsigned short*)alloc(NTOK * 1024 * 2);

  const int n1_4 = (int)(NTOK * 1024 / 4);
  k_split2<<<2048, 256, 0, stream>>>(query, qxh, qxl, n1_4);
  k_split2<<<2048, 256, 0, stream>>>(keyi, kxh, kxl, n1_4);
  k_cvt<<<2048, 256, 0, stream>>>(value, vx, n1_4);
  k_split2<<<1024, 256, 0, stream>>>(ipw, wh, wl, 2048 * 1024 / 4);
  k_cvt<<<512, 256, 0, stream>>>(ipw + 2048 * 1024, wv, 1024 * 1024 / 4);
  k_cvt<<<512, 256, 0, stream>>>(outw, ow, 1024 * 1024 / 4);

  k_proj_qk<<<dim3(32, 8, 2), 256, 0, stream>>>(qxh, qxl, kxh, kxl, wh, wl, ipb, qh, ql, kh, kl);
  k_proj_v<<<dim3(8, 32), 256, 0, stream>>>(wv, vx, ipb, VT);
  k_attn_pv<<<4096, 256, 0, stream>>>(qh, ql, kh, kl, VT, posb, attn, oc);
  k_outproj<<<dim3(32, 8), 256, 0, stream>>>(oc, ow, outb, out);
}